// Round 18
// baseline (336.278 us; speedup 1.0000x reference)
//
#include <hip/hip_runtime.h>
#include <hip/hip_bf16.h>

typedef unsigned short u16;
typedef __attribute__((ext_vector_type(8))) short bf16x8;
typedef __attribute__((ext_vector_type(4))) float floatx4;

__device__ inline float u2f(unsigned u) { union { unsigned i; float f; } x; x.i = u; return x.f; }
__device__ inline float bflo(unsigned p) { return u2f(p << 16); }
__device__ inline float bfhi(unsigned p) { return u2f(p & 0xffff0000u); }
__device__ inline u16 f2bf(float f) {
    union { __hip_bfloat16 h; u16 u; } x;
    x.h = __float2bfloat16(f);
    return x.u;
}
__device__ inline unsigned pk2bf(float lo, float hi) {
    return ((unsigned)f2bf(hi) << 16) | f2bf(lo);
}

#define SCLQ 0.18033688011f   // 0.125 * log2(e), folded into Q

#define GLDS(g, l) __builtin_amdgcn_global_load_lds( \
    (const __attribute__((address_space(1))) void*)(g), \
    (__attribute__((address_space(3))) void*)(l), 16, 0, 0)

// ---------------------------------------------------------------------------
// bf16 MFMA GEMM (frozen from round 17): block (MW*32)x(NF*32), 4 waves,
// 16x16x32 MFMA, BK=32, XCD swizzle, 3-buffer counted-vmcnt pipeline.
// EPI: 0 bf16, 1 +relu, 2 +bf16 res, 5 seg QKV (Q*SCLQ), 6 seg KV,
//      7 split-K f32 partials (z0 -> Cv +bias, z1 -> o1), 8 bf16*SCLQ.
// ---------------------------------------------------------------------------
template<int EPI, int NF, int MW>
__global__ __launch_bounds__(256, (MW == 8) ? 2 : 3) void gemm_mfma(
        const u16* __restrict__ A, const u16* __restrict__ Bt,
        const float* __restrict__ bias, const u16* __restrict__ res,
        void* __restrict__ Cv, u16* __restrict__ o1, u16* __restrict__ o2,
        int N, int K)
{
    constexpr int BN = NF * 32;
    constexpr int BM = MW * 32;
    constexpr int MFR = BM / 32;
    constexpr int ALOADS = BM / 64;
    constexpr int BLOADS = BN / 64;
    constexpr int LOADS = ALOADS + BLOADS;

    __shared__ u16 As0[BM * 32];
    __shared__ u16 Bs0[BN * 32];
    __shared__ u16 As1[BM * 32];
    __shared__ u16 Bs1[BN * 32];
    __shared__ u16 As2[BM * 32];
    __shared__ u16 Bs2[BN * 32];

    const int tid = threadIdx.x;
    const int lane = tid & 63, wv = tid >> 6;
    const int wr = wv >> 1, wc = wv & 1;

    const int gx = gridDim.x;
    const int nwg = gx * gridDim.y;
    const int bid0 = blockIdx.y * gx + blockIdx.x;
    const int nbid = (bid0 & 7) * (nwg >> 3) + (bid0 >> 3);
    const int bx = nbid % gx, by = nbid / gx;
    const int row0 = by * BM, col0 = bx * BN;

    const int Keff = (EPI == 7) ? (K >> 1) : K;
    const int k0off = (EPI == 7) ? blockIdx.z * Keff : 0;

    const u16* pa[ALOADS];
    int ldst[ALOADS];
    #pragma unroll
    for (int i = 0; i < ALOADS; ++i) {
        const int idx = i * 256 + tid;
        const int r = idx >> 2;
        const int kob = (idx & 3) << 4;
        const int sw = kob ^ (((r >> 1) & 3) << 4);
        pa[i] = A + (size_t)(row0 + r) * K + k0off + (sw >> 1);
        ldst[i] = idx * 8;
    }
    const u16* pb[BLOADS];
    int ldstB[BLOADS];
    #pragma unroll
    for (int i = 0; i < BLOADS; ++i) {
        const int idx = i * 256 + tid;
        const int r = idx >> 2;
        const int kob = (idx & 3) << 4;
        const int sw = kob ^ (((r >> 1) & 3) << 4);
        pb[i] = Bt + (size_t)(col0 + r) * K + k0off + (sw >> 1);
        ldstB[i] = idx * 8;
    }

    int offa[MFR], offb[NF];
    const int rsel = lane & 15, slot = lane >> 4;
    #pragma unroll
    for (int m = 0; m < MFR; ++m) {
        const int ra = wr * (BM / 2) + m * 16 + rsel;
        offa[m] = ra * 32 + (((slot << 4) ^ (((ra >> 1) & 3) << 4)) >> 1);
    }
    #pragma unroll
    for (int n = 0; n < NF; ++n) {
        const int rb = wc * (NF * 16) + n * 16 + rsel;
        offb[n] = rb * 32 + (((slot << 4) ^ (((rb >> 1) & 3) << 4)) >> 1);
    }

    floatx4 acc[MFR][NF] = {};

#define STAGE(AA, BB, t) do {                                   \
        const int ko_ = (t) << 5;                               \
        _Pragma("unroll")                                       \
        for (int i = 0; i < ALOADS; ++i)                        \
            GLDS(pa[i] + ko_, &AA[ldst[i]]);                    \
        _Pragma("unroll")                                       \
        for (int i = 0; i < BLOADS; ++i)                        \
            GLDS(pb[i] + ko_, &BB[ldstB[i]]);                   \
    } while (0)

#define COMPUTE(AA, BB) do {                                    \
        bf16x8 af[MFR], bfr[NF];                                \
        _Pragma("unroll")                                       \
        for (int m = 0; m < MFR; ++m) af[m] = *(const bf16x8*)&AA[offa[m]]; \
        _Pragma("unroll")                                       \
        for (int n = 0; n < NF; ++n) bfr[n] = *(const bf16x8*)&BB[offb[n]]; \
        _Pragma("unroll")                                       \
        for (int m = 0; m < MFR; ++m)                           \
            _Pragma("unroll")                                   \
            for (int n = 0; n < NF; ++n)                        \
                acc[m][n] = __builtin_amdgcn_mfma_f32_16x16x32_bf16( \
                        af[m], bfr[n], acc[m][n], 0, 0, 0);     \
    } while (0)

#define PHASE(CA, CB, NA, NB, t) do {                           \
        if ((t) < nkt - 1) {                                    \
            if constexpr (LOADS == 6)                           \
                asm volatile("s_waitcnt vmcnt(6)" ::: "memory");\
            else if constexpr (LOADS == 4)                      \
                asm volatile("s_waitcnt vmcnt(4)" ::: "memory");\
            else                                                \
                asm volatile("s_waitcnt vmcnt(3)" ::: "memory");\
        } else {                                                \
            asm volatile("s_waitcnt vmcnt(0)" ::: "memory");    \
        }                                                       \
        __builtin_amdgcn_s_barrier();                           \
        __builtin_amdgcn_sched_barrier(0);                      \
        if ((t) + 2 < nkt) STAGE(NA, NB, (t) + 2);              \
        COMPUTE(CA, CB);                                        \
    } while (0)

    const int nkt = Keff >> 5;
    STAGE(As0, Bs0, 0);
    STAGE(As1, Bs1, 1);
    int t = 0;
    for (; t + 3 <= nkt; t += 3) {
        PHASE(As0, Bs0, As2, Bs2, t);
        PHASE(As1, Bs1, As0, Bs0, t + 1);
        PHASE(As2, Bs2, As1, Bs1, t + 2);
    }
    if (t < nkt)     PHASE(As0, Bs0, As2, Bs2, t);
    if (t + 1 < nkt) PHASE(As1, Bs1, As0, Bs0, t + 1);
#undef STAGE
#undef COMPUTE
#undef PHASE

    const int cr4 = (lane >> 4) * 4;
    const int cc = lane & 15;

    if (EPI == 7) {
        float* dst = (blockIdx.z == 0) ? (float*)Cv : (float*)o1;
        const bool addb = (blockIdx.z == 0);
        #pragma unroll
        for (int n = 0; n < NF; ++n) {
            const int col = col0 + wc * (NF * 16) + n * 16 + cc;
            const float bv = addb ? bias[col] : 0.f;
            #pragma unroll
            for (int m = 0; m < MFR; ++m) {
                const int rowb = row0 + wr * (BM / 2) + m * 16 + cr4;
                #pragma unroll
                for (int r = 0; r < 4; ++r)
                    dst[(size_t)(rowb + r) * N + col] = acc[m][n][r] + bv;
            }
        }
        return;
    }

    if (EPI == 5 || EPI == 6) {
        const int seg = col0 >> 10;
        const int vtseg = (EPI == 5) ? 2 : 1;
        u16* dst;
        if (EPI == 5) dst = (seg == 0) ? (u16*)Cv : (seg == 1 ? o1 : o2);
        else          dst = (seg == 0) ? (u16*)Cv : o1;

        if (seg == vtseg) {
            #pragma unroll
            for (int n = 0; n < NF; ++n) {
                const int col = col0 + wc * (NF * 16) + n * 16 + cc;
                const float bv = bias[col];
                const int vcol = col & 1023;
                const int h = vcol >> 6, d = vcol & 63;
                #pragma unroll
                for (int m = 0; m < MFR; ++m) {
                    const int tk = row0 + wr * (BM / 2) + m * 16 + cr4;
                    const int b = tk >> 10;
                    ushort4 o4;
                    o4.x = f2bf(acc[m][n][0] + bv);
                    o4.y = f2bf(acc[m][n][1] + bv);
                    o4.z = f2bf(acc[m][n][2] + bv);
                    o4.w = f2bf(acc[m][n][3] + bv);
                    *(ushort4*)(dst +
                        (((size_t)(b * 16 + h) * 64 + d) * 1024 + (tk & 1023))) = o4;
                }
            }
        } else {
            const float osc = (EPI == 5 && seg == 0) ? SCLQ : 1.f;
            #pragma unroll
            for (int n = 0; n < NF; ++n) {
                const int col = col0 + wc * (NF * 16) + n * 16 + cc;
                const float bv = bias[col];
                const int oc = col & 1023;
                #pragma unroll
                for (int m = 0; m < MFR; ++m) {
                    const int rowb = row0 + wr * (BM / 2) + m * 16 + cr4;
                    #pragma unroll
                    for (int r = 0; r < 4; ++r)
                        dst[(size_t)(rowb + r) * 1024 + oc] = f2bf((acc[m][n][r] + bv) * osc);
                }
            }
        }
        return;
    }

    #pragma unroll
    for (int n = 0; n < NF; ++n) {
        const int col = col0 + wc * (NF * 16) + n * 16 + cc;
        const float bv = bias[col];
        #pragma unroll
        for (int m = 0; m < MFR; ++m) {
            const int rowb = row0 + wr * (BM / 2) + m * 16 + cr4;
            #pragma unroll
            for (int r = 0; r < 4; ++r) {
                float v = acc[m][n][r] + bv;
                const size_t o = (size_t)(rowb + r) * N + col;
                if (EPI == 2) v += u2f((unsigned)res[o] << 16);
                if (EPI == 1) v = fmaxf(v, 0.f);
                if (EPI == 8) v *= SCLQ;
                ((u16*)Cv)[o] = f2bf(v);
            }
        }
    }
}

// ---------------------------------------------------------------------------
// Fused prep (frozen from round 17).
// ---------------------------------------------------------------------------
struct PrepArgs {
    const float* w[10];
    u16* o[10];
    const float* tgt; const float* mem;
    u16* tgtb; u16* memb;
    const float* bq; const float* bk; const float* bv;
    const float* cbk; const float* cbv;
    float* biasQKV; float* biasKV;
};

__global__ __launch_bounds__(256) void prep_kernel(PrepArgs p)
{
    __shared__ float ts[64][65];
    const int tid = threadIdx.x;
    int bid = blockIdx.x;

    if (bid < 4096) {
        int w, n0, k0, K, N;
        if (bid < 2048) {
            w = bid >> 8;
            const int t = bid & 255;
            n0 = (t & 15) * 64; k0 = ((t >> 4) & 15) * 64; K = 1024; N = 1024;
        } else if (bid < 3072) {
            w = 8;
            const int t = bid - 2048;
            n0 = (t & 63) * 64; k0 = (t >> 6) * 64; K = 1024; N = 4096;
        } else {
            w = 9;
            const int t = bid - 3072;
            n0 = (t & 15) * 64; k0 = (t >> 4) * 64; K = 4096; N = 1024;
        }
        const float* __restrict__ W = p.w[w];
        u16* __restrict__ Wt = p.o[w];
        const int tr = tid >> 4, tc4 = (tid & 15) * 4;
        #pragma unroll
        for (int i = 0; i < 4; ++i) {
            const float4 v = *(const float4*)(W + (size_t)(k0 + tr + i * 16) * N + n0 + tc4);
            ts[tr + i * 16][tc4 + 0] = v.x;
            ts[tr + i * 16][tc4 + 1] = v.y;
            ts[tr + i * 16][tc4 + 2] = v.z;
            ts[tr + i * 16][tc4 + 3] = v.w;
        }
        __syncthreads();
        #pragma unroll
        for (int i = 0; i < 4; ++i) {
            const int nr = tr + i * 16;
            ushort4 o;
            o.x = f2bf(ts[tc4 + 0][nr]);
            o.y = f2bf(ts[tc4 + 1][nr]);
            o.z = f2bf(ts[tc4 + 2][nr]);
            o.w = f2bf(ts[tc4 + 3][nr]);
            *(ushort4*)(Wt + (size_t)(n0 + nr) * K + k0 + tc4) = o;
        }
        return;
    }
    bid -= 4096;
    if (bid < 4096) {
        const int i = bid * 256 + tid;
        const float4 v = ((const float4*)p.tgt)[i];
        ushort4 o;
        o.x = f2bf(v.x); o.y = f2bf(v.y); o.z = f2bf(v.z); o.w = f2bf(v.w);
        ((ushort4*)p.tgtb)[i] = o;
        return;
    }
    bid -= 4096;
    if (bid < 4096) {
        const int i = bid * 256 + tid;
        const float4 v = ((const float4*)p.mem)[i];
        ushort4 o;
        o.x = f2bf(v.x); o.y = f2bf(v.y); o.z = f2bf(v.z); o.w = f2bf(v.w);
        ((ushort4*)p.memb)[i] = o;
        return;
    }
    bid -= 4096;
    const int i = bid * 256 + tid;
    if (i < 3072)
        p.biasQKV[i] = (i < 1024) ? p.bq[i] : (i < 2048 ? p.bk[i - 1024] : p.bv[i - 2048]);
    if (i < 2048)
        p.biasKV[i] = (i < 1024) ? p.cbk[i] : p.cbv[i - 1024];
}

// ---------------------------------------------------------------------------
// MFMA flash attention, swapped-operand, static-max softmax, TWO q-tiles
// per block (A = tile 2j, B = tile 2j+1) sharing the K/V stream:
// staging per q-tile halved; kf/vf fragments register-shared across A/B.
// Per kt: 8 kf reads -> 16 QK MFMAs; 8 vf reads -> 8 PV MFMAs.
// Causal: tile X active iff kt <= tile_index(X); diagonal mask when equal.
// Grid (64, 8). LDS 32 KB (K 8 + V 8 + PsA 8 + PsB 8).
// ---------------------------------------------------------------------------
template<int CAUSAL>
__global__ __launch_bounds__(256) void fattn_mfma(
        const u16* __restrict__ Q, const u16* __restrict__ K,
        const u16* __restrict__ Vt, u16* __restrict__ O)
{
    __shared__ u16 Ks[64 * 64];
    __shared__ u16 Vs[64 * 64];
    __shared__ u16 PsA[64 * 64];
    __shared__ u16 PsB[64 * 64];

    const int tid = threadIdx.x;
    const int lane = tid & 63, wv = tid >> 6;
    const int g = lane >> 4, qx = lane & 15;
    const int bh = blockIdx.x;
    const int b = bh >> 4, h = bh & 15;
    const int jt = blockIdx.y;
    const int tiA = 2 * jt, tiB = 2 * jt + 1;        // q-tile indices
    const int q0A = tiA * 64, q0B = tiB * 64;

    const size_t qkbase = (size_t)b * (1024 * 1024) + (size_t)h * 64;
    const size_t vtbase = (size_t)bh * 64 * 1024;

    const int qr = wv * 16 + qx;                     // tile-local q row
    const int swzq = (qr & 7) << 4;

    bf16x8 qfA[2], qfB[2];
    #pragma unroll
    for (int ks = 0; ks < 2; ++ks) {
        qfA[ks] = *(const bf16x8*)(Q + qkbase + (size_t)(q0A + qr) * 1024 + ks * 32 + g * 8);
        qfB[ks] = *(const bf16x8*)(Q + qkbase + (size_t)(q0B + qr) * 1024 + ks * 32 + g * 8);
    }

    const int r0 = tid >> 3, s0 = tid & 7;

    float lA = 0.f, lB = 0.f;
    floatx4 oA[4] = {}, oB[4] = {};

    const int ktmax = CAUSAL ? tiB : 15;
    for (int kt = 0; kt <= ktmax; ++kt) {
        const bool doA = !CAUSAL || (kt <= tiA);     // block-uniform
        __syncthreads();
        #pragma unroll
        for (int i = 0; i < 2; ++i) {
            const int r = i * 32 + r0;
            const uint4 kv = *(const uint4*)(K + qkbase + (size_t)(kt * 64 + r) * 1024 + s0 * 8);
            *(uint4*)((char*)Ks + r * 128 + ((s0 ^ (r & 7)) << 4)) = kv;
            const uint4 vv = *(const uint4*)(Vt + vtbase + (size_t)r * 1024 + kt * 64 + s0 * 8);
            *(uint4*)((char*)Vs + r * 128 + ((s0 ^ (r & 7)) << 4)) = vv;
        }
        __syncthreads();

        // S^T = mfma(K, Q) for both q-tiles, kf register-shared
        floatx4 saA[4] = {}, saB[4] = {};
        #pragma unroll
        for (int ks = 0; ks < 2; ++ks) {
            #pragma unroll
            for (int m = 0; m < 4; ++m) {
                const int rr = m * 16 + qx;
                const int sl = ks * 4 + g;
                const bf16x8 kf = *(const bf16x8*)((char*)Ks + rr * 128 + ((sl ^ (rr & 7)) << 4));
                if (doA)
                    saA[m] = __builtin_amdgcn_mfma_f32_16x16x32_bf16(kf, qfA[ks], saA[m], 0, 0, 0);
                saB[m] = __builtin_amdgcn_mfma_f32_16x16x32_bf16(kf, qfB[ks], saB[m], 0, 0, 0);
            }
        }

        // static-max softmax + P pack (per tile)
        if (doA) {
            float rs = 0.f;
            float p[4][4];
            #pragma unroll
            for (int m = 0; m < 4; ++m)
                #pragma unroll
                for (int r = 0; r < 4; ++r) {
                    float e = exp2f(saA[m][r]);
                    if (CAUSAL && kt == tiA) {
                        const int kl = m * 16 + g * 4 + r;
                        if (kl > qr) e = 0.f;
                    }
                    p[m][r] = e;
                    rs += e;
                }
            rs += __shfl_xor(rs, 16);
            rs += __shfl_xor(rs, 32);
            lA += rs;
            #pragma unroll
            for (int m = 0; m < 4; ++m) {
                uint2 pk;
                pk.x = pk2bf(p[m][0], p[m][1]);
                pk.y = pk2bf(p[m][2], p[m][3]);
                *(uint2*)((char*)PsA + qr * 128 + ((m * 32 + g * 8) ^ swzq)) = pk;
            }
        }
        {
            float rs = 0.f;
            float p[4][4];
            #pragma unroll
            for (int m = 0; m < 4; ++m)
                #pragma unroll
                for (int r = 0; r < 4; ++r) {
                    float e = exp2f(saB[m][r]);
                    if (CAUSAL && kt == tiB) {
                        const int kl = m * 16 + g * 4 + r;
                        if (kl > qr) e = 0.f;
                    }
                    p[m][r] = e;
                    rs += e;
                }
            rs += __shfl_xor(rs, 16);
            rs += __shfl_xor(rs, 32);
            lB += rs;
            #pragma unroll
            for (int m = 0; m < 4; ++m) {
                uint2 pk;
                pk.x = pk2bf(p[m][0], p[m][1]);
                pk.y = pk2bf(p[m][2], p[m][3]);
                *(uint2*)((char*)PsB + qr * 128 + ((m * 32 + g * 8) ^ swzq)) = pk;
            }
        }

        // O^T += mfma(Vt, P^T), vf register-shared across A/B
        #pragma unroll
        for (int ks2 = 0; ks2 < 2; ++ks2) {
            bf16x8 vf[4];
            #pragma unroll
            for (int n = 0; n < 4; ++n) {
                const int rv = n * 16 + qx;
                const int sl = ks2 * 4 + g;
                vf[n] = *(const bf16x8*)((char*)Vs + rv * 128 + ((sl ^ (rv & 7)) << 4));
            }
            if (doA) {
                const bf16x8 pfA = *(const bf16x8*)((char*)PsA + qr * 128 + ((ks2 * 64 + g * 16) ^ swzq));
                #pragma unroll
                for (int n = 0; n < 4; ++n)
                    oA[n] = __builtin_amdgcn_mfma_f32_16x16x32_bf16(vf[n], pfA, oA[n], 0, 0, 0);
            }
            const bf16x8 pfB = *(const bf16x8*)((char*)PsB + qr * 128 + ((ks2 * 64 + g * 16) ^ swzq));
            #pragma unroll
            for (int n = 0; n < 4; ++n)
                oB[n] = __builtin_amdgcn_mfma_f32_16x16x32_bf16(vf[n], pfB, oB[n], 0, 0, 0);
        }
    }

    // epilogue: normalize + transpose each tile through its Ps (wave-private)
    const float invA = 1.f / lA, invB = 1.f / lB;
    #pragma unroll
    for (int n = 0; n < 4; ++n) {
        uint2 ovA, ovB;
        ovA.x = pk2bf(oA[n][0] * invA, oA[n][1] * invA);
        ovA.y = pk2bf(oA[n][2] * invA, oA[n][3] * invA);
        *(uint2*)((char*)PsA + qr * 128 + ((n * 32 + g * 8) ^ swzq)) = ovA;
        ovB.x = pk2bf(oB[n][0] * invB, oB[n][1] * invB);
        ovB.y = pk2bf(oB[n][2] * invB, oB[n][3] * invB);
        *(uint2*)((char*)PsB + qr * 128 + ((n * 32 + g * 8) ^ swzq)) = ovB;
    }
    const int orow = wv * 16 + (lane >> 2);
    const int swzo = (orow & 7) << 4;
    #pragma unroll
    for (int i = 0; i < 2; ++i) {
        const int cb = ((lane & 3) * 2 + i) * 16;
        const uint4 ovA = *(const uint4*)((char*)PsA + orow * 128 + (cb ^ swzo));
        *(uint4*)(O + qkbase + (size_t)(q0A + orow) * 1024 + cb / 2) = ovA;
        const uint4 ovB = *(const uint4*)((char*)PsB + orow * 128 + (cb ^ swzo));
        *(uint4*)(O + qkbase + (size_t)(q0B + orow) * 1024 + cb / 2) = ovB;
    }
}

// ---------------------------------------------------------------------------
// LayerNorm, bf16 in/out, fp32 stats (frozen).
// ---------------------------------------------------------------------------
__global__ __launch_bounds__(256) void ln_bf16_kernel(
        const u16* __restrict__ X, const float* __restrict__ g,
        const float* __restrict__ bta, u16* __restrict__ Y)
{
    __shared__ float red[4];
    const int row = blockIdx.x, tid = threadIdx.x;
    const int wave = tid >> 6, lane = tid & 63;

    const uint2 u = *(const uint2*)(X + (size_t)row * 1024 + tid * 4);
    const float x0 = bflo(u.x), x1 = bfhi(u.x), x2 = bflo(u.y), x3 = bfhi(u.y);

    float s = x0 + x1 + x2 + x3;
    #pragma unroll
    for (int off = 32; off; off >>= 1) s += __shfl_xor(s, off);
    if (lane == 0) red[wave] = s;
    __syncthreads();
    const float mu = (red[0] + red[1] + red[2] + red[3]) * (1.f / 1024.f);
    __syncthreads();

    const float d0 = x0 - mu, d1 = x1 - mu, d2 = x2 - mu, d3 = x3 - mu;
    float s2 = d0 * d0 + d1 * d1 + d2 * d2 + d3 * d3;
    #pragma unroll
    for (int off = 32; off; off >>= 1) s2 += __shfl_xor(s2, off);
    if (lane == 0) red[wave] = s2;
    __syncthreads();
    const float var = (red[0] + red[1] + red[2] + red[3]) * (1.f / 1024.f);
    const float rs = rsqrtf(var + 1e-5f);

    const float4 gg = ((const float4*)g)[tid];
    const float4 bb = ((const float4*)bta)[tid];
    ushort4 o;
    o.x = f2bf(d0 * rs * gg.x + bb.x);
    o.y = f2bf(d1 * rs * gg.y + bb.y);
    o.z = f2bf(d2 * rs * gg.z + bb.z);
    o.w = f2bf(d3 * rs * gg.w + bb.w);
    *(ushort4*)(Y + (size_t)row * 1024 + tid * 4) = o;
}

// final LayerNorm: X0 + X1 (f32 split-K partials) + bf16 residual -> f32 out
__global__ __launch_bounds__(256) void ln_res_kernel(
        const float* X0, const float* __restrict__ X1,
        const u16* __restrict__ res, const float* __restrict__ g,
        const float* __restrict__ bta, float* Y)
{
    __shared__ float red[4];
    const int row = blockIdx.x;
    const int tid = threadIdx.x;
    const int wave = tid >> 6, lane = tid & 63;

    const float4 v0 = ((const float4*)(X0 + (size_t)row * 1024))[tid];
    const float4 v1 = ((const float4*)(X1 + (size_t)row * 1024))[tid];
    const uint2 u = *(const uint2*)(res + (size_t)row * 1024 + tid * 4);
    const float x0 = v0.x + v1.x + bflo(u.x), x1 = v0.y + v1.y + bfhi(u.x);
    const float x2 = v0.z + v1.z + bflo(u.y), x3 = v0.w + v1.w + bfhi(u.y);

    float s = x0 + x1 + x2 + x3;
    #pragma unroll
    for (int off = 32; off; off >>= 1) s += __shfl_xor(s, off);
    if (lane == 0) red[wave] = s;
    __syncthreads();
    const float mu = (red[0] + red[1] + red[2] + red[3]) * (1.f / 1024.f);
    __syncthreads();

    const float d0 = x0 - mu, d1 = x1 - mu, d2 = x2 - mu, d3 = x3 - mu;
    float s2 = d0 * d0 + d1 * d1 + d2 * d2 + d3 * d3;
    #pragma unroll
    for (int off = 32; off; off >>= 1) s2 += __shfl_xor(s2, off);
    if (lane == 0) red[wave] = s2;
    __syncthreads();
    const float var = (red[0] + red[1] + red[2] + red[3]) * (1.f / 1024.f);
    const float rs = rsqrtf(var + 1e-5f);

    const float4 gg = ((const float4*)g)[tid];
    const float4 bb = ((const float4*)bta)[tid];
    float4 o;
    o.x = d0 * rs * gg.x + bb.x;
    o.y = d1 * rs * gg.y + bb.y;
    o.z = d2 * rs * gg.z + bb.z;
    o.w = d3 * rs * gg.w + bb.w;
    ((float4*)(Y + (size_t)row * 1024))[tid] = o;
}

// ---------------------------------------------------------------------------
extern "C" void kernel_launch(void* const* d_in, const int* in_sizes, int n_in,
                              void* d_out, int out_size, void* d_ws, size_t ws_size,
                              hipStream_t stream)
{
    const float* tgt    = (const float*)d_in[0];
    const float* mem    = (const float*)d_in[1];
    const float* sa_wq  = (const float*)d_in[3];
    const float* sa_bq  = (const float*)d_in[4];
    const float* sa_wk  = (const float*)d_in[5];
    const float* sa_bk  = (const float*)d_in[6];
    const float* sa_wv  = (const float*)d_in[7];
    const float* sa_bv  = (const float*)d_in[8];
    const float* sa_wo  = (const float*)d_in[9];
    const float* sa_bo  = (const float*)d_in[10];
    const float* ca_wq  = (const float*)d_in[11];
    const float* ca_bq  = (const float*)d_in[12];
    const float* ca_wk  = (const float*)d_in[13];
    const float* ca_bk  = (const float*)d_in[14];
    const float* ca_wv  = (const float*)d_in[15];
    const float* ca_bv  = (const float*)d_in[16];
    const float* ca_wo  = (const float*)d_in[17];
    const float* ca_bo  = (const float*)d_in[18];
    const float* ffn_w1 = (const float*)d_in[19];
    const float* ffn_b1 = (const float*)d_in[20];
    const float* ffn_w2 = (const float*)d_in[21];
    const float* ffn_b2 = (const float*)d_in[22];
    const float* ln1_g  = (const float*)d_in[23];
    const float* ln1_b  = (const float*)d_in[24];
    const float* ln2_g  = (const float*)d_in[25];
    const float* ln2_b  = (const float*)d_in[26];
    const float* ln3_g  = (const float*)d_in[27];
    const float* ln3_b  = (const float*)d_in[28];

    float* out = (float*)d_out;
    u16* wsb = (u16*)d_ws;
    const size_t M1 = 1024 * 1024;

    u16* Wsq = wsb + 0 * M1;
    u16* Wsk = wsb + 1 * M1;
    u16* Wsv = wsb + 2 * M1;
    u16* Wso = wsb + 3 * M1;
    u16* Wcq = wsb + 4 * M1;
    u16* Wck = wsb + 5 * M1;
    u16* Wcv = wsb + 6 * M1;
    u16* Wco = wsb + 7 * M1;
    u16* Wf1 = wsb + 8 * M1;
    u16* Wf2 = wsb + 12 * M1;

    u16* sl = wsb + 16 * M1;
    u16* s0 = sl + 0 * 4 * M1;
    u16* s1 = sl + 4 * M1;
    u16* s2 = sl + 8 * M1;
    u16* s3 = sl + 12 * M1;
    u16* s4 = sl + 16 * M1;
    u16* s5 = sl + 20 * M1;
    u16* H  = s0;

    float* part1 = (float*)wsb;

    float* biasQKV = (float*)(wsb + 40 * M1);
    float* biasKV  = biasQKV + 3072;

    const dim3 blk(256);
    const dim3 gqkv(24, 32);
    const dim3 gkv(16, 32);
    const dim3 g1(16, 32);
    const dim3 g4(32, 16);
    const dim3 gf2(8, 32, 2);
    const dim3 ga(64, 8);       // attention: 2 q-tiles per block
    const dim3 gln(4096);

    PrepArgs pa;
    pa.w[0] = sa_wq; pa.o[0] = Wsq;
    pa.w[1] = sa_wk; pa.o[1] = Wsk;
    pa.w[2] = sa_wv; pa.o[2] = Wsv;
    pa.w[3] = sa_wo; pa.o[3] = Wso;
    pa.w[4] = ca_wq; pa.o[4] = Wcq;
    pa.w[5] = ca_wk; pa.o[5] = Wck;
    pa.w[6] = ca_wv; pa.o[6] = Wcv;
    pa.w[7] = ca_wo; pa.o[7] = Wco;
    pa.w[8] = ffn_w1; pa.o[8] = Wf1;
    pa.w[9] = ffn_w2; pa.o[9] = Wf2;
    pa.tgt = tgt; pa.mem = mem; pa.tgtb = s0; pa.memb = s1;
    pa.bq = sa_bq; pa.bk = sa_bk; pa.bv = sa_bv;
    pa.cbk = ca_bk; pa.cbv = ca_bv;
    pa.biasQKV = biasQKV; pa.biasKV = biasKV;
    prep_kernel<<<12308, blk, 0, stream>>>(pa);

    // ---- self-attention ----
    gemm_mfma<5, 4, 4><<<gqkv, blk, 0, stream>>>(s0, Wsq, biasQKV, nullptr,
                                                 s2, s3, s4, 3072, 1024);
    fattn_mfma<1><<<ga, blk, 0, stream>>>(s2, s3, s4, s5);
    gemm_mfma<2, 2, 4><<<g1, blk, 0, stream>>>(s5, Wso, sa_bo, s0, s2, nullptr, nullptr, 1024, 1024);
    ln_bf16_kernel<<<gln, blk, 0, stream>>>(s2, ln1_g, ln1_b, s3);

    // ---- cross-attention ----
    gemm_mfma<8, 2, 4><<<g1, blk, 0, stream>>>(s3, Wcq, ca_bq, nullptr, s2, nullptr, nullptr, 1024, 1024);
    gemm_mfma<6, 4, 4><<<gkv, blk, 0, stream>>>(s1, Wck, biasKV, nullptr,
                                                s4, s5, nullptr, 2048, 1024);
    fattn_mfma<0><<<ga, blk, 0, stream>>>(s2, s4, s5, s0);
    gemm_mfma<2, 2, 4><<<g1, blk, 0, stream>>>(s0, Wco, ca_bo, s3, s2, nullptr, nullptr, 1024, 1024);
    ln_bf16_kernel<<<gln, blk, 0, stream>>>(s2, ln2_g, ln2_b, s4);

    // ---- FFN ----
    gemm_mfma<1, 4, 8><<<g4, blk, 0, stream>>>(s4, Wf1, ffn_b1, nullptr, H, nullptr, nullptr, 4096, 1024);
    gemm_mfma<7, 4, 4><<<gf2, blk, 0, stream>>>(H, Wf2, ffn_b2, nullptr, out,
                                                (u16*)part1, nullptr, 1024, 4096);
    ln_res_kernel<<<gln, blk, 0, stream>>>(out, part1, s4, ln3_g, ln3_b, out);
}

// Round 19
// 318.420 us; speedup vs baseline: 1.0561x; 1.0561x over previous
//
#include <hip/hip_runtime.h>
#include <hip/hip_bf16.h>

typedef unsigned short u16;
typedef __attribute__((ext_vector_type(8))) short bf16x8;
typedef __attribute__((ext_vector_type(4))) float floatx4;

__device__ inline float u2f(unsigned u) { union { unsigned i; float f; } x; x.i = u; return x.f; }
__device__ inline float bflo(unsigned p) { return u2f(p << 16); }
__device__ inline float bfhi(unsigned p) { return u2f(p & 0xffff0000u); }
__device__ inline u16 f2bf(float f) {
    union { __hip_bfloat16 h; u16 u; } x;
    x.h = __float2bfloat16(f);
    return x.u;
}
__device__ inline unsigned pk2bf(float lo, float hi) {
    return ((unsigned)f2bf(hi) << 16) | f2bf(lo);
}

#define SCLQ 0.18033688011f   // 0.125 * log2(e), folded into Q

#define GLDS(g, l) __builtin_amdgcn_global_load_lds( \
    (const __attribute__((address_space(1))) void*)(g), \
    (__attribute__((address_space(3))) void*)(l), 16, 0, 0)

// ---------------------------------------------------------------------------
// bf16 MFMA GEMM: C[M,N] = A[M,K] @ Bt[N,K]^T + bias (+res) (+relu)
// Block tile (MW*32) x (NF*32), 4 waves (2x2), 16x16x32 MFMA, BK=32,
// XCD-chunked swizzle, 3-buffer counted-vmcnt pipeline (stage t+2, steady
// wait vmcnt(LOADS), drain only on last tile).
//   MW=4: 128-row block;  MW=8: 256-row block (FFN1, better MFMA:ds ratio).
// EPI: 0 bf16, 1 +relu, 2 +bf16 res, 5 seg QKV (Q scaled by SCLQ), 6 seg KV,
//      7 split-K f32 partials (z0 -> Cv +bias, z1 -> o1), 8 bf16 * SCLQ.
// Vt layout: Vt[b*16+h][d][t], t fast.
// ---------------------------------------------------------------------------
template<int EPI, int NF, int MW>
__global__ __launch_bounds__(256, (MW == 8) ? 2 : 3) void gemm_mfma(
        const u16* __restrict__ A, const u16* __restrict__ Bt,
        const float* __restrict__ bias, const u16* __restrict__ res,
        void* __restrict__ Cv, u16* __restrict__ o1, u16* __restrict__ o2,
        int N, int K)
{
    constexpr int BN = NF * 32;
    constexpr int BM = MW * 32;
    constexpr int MFR = BM / 32;
    constexpr int ALOADS = BM / 64;
    constexpr int BLOADS = BN / 64;
    constexpr int LOADS = ALOADS + BLOADS;

    __shared__ u16 As0[BM * 32];
    __shared__ u16 Bs0[BN * 32];
    __shared__ u16 As1[BM * 32];
    __shared__ u16 Bs1[BN * 32];
    __shared__ u16 As2[BM * 32];
    __shared__ u16 Bs2[BN * 32];

    const int tid = threadIdx.x;
    const int lane = tid & 63, wv = tid >> 6;
    const int wr = wv >> 1, wc = wv & 1;

    const int gx = gridDim.x;
    const int nwg = gx * gridDim.y;
    const int bid0 = blockIdx.y * gx + blockIdx.x;
    const int nbid = (bid0 & 7) * (nwg >> 3) + (bid0 >> 3);
    const int bx = nbid % gx, by = nbid / gx;
    const int row0 = by * BM, col0 = bx * BN;

    const int Keff = (EPI == 7) ? (K >> 1) : K;
    const int k0off = (EPI == 7) ? blockIdx.z * Keff : 0;

    const u16* pa[ALOADS];
    int ldst[ALOADS];
    #pragma unroll
    for (int i = 0; i < ALOADS; ++i) {
        const int idx = i * 256 + tid;
        const int r = idx >> 2;
        const int kob = (idx & 3) << 4;
        const int sw = kob ^ (((r >> 1) & 3) << 4);
        pa[i] = A + (size_t)(row0 + r) * K + k0off + (sw >> 1);
        ldst[i] = idx * 8;
    }
    const u16* pb[BLOADS];
    int ldstB[BLOADS];
    #pragma unroll
    for (int i = 0; i < BLOADS; ++i) {
        const int idx = i * 256 + tid;
        const int r = idx >> 2;
        const int kob = (idx & 3) << 4;
        const int sw = kob ^ (((r >> 1) & 3) << 4);
        pb[i] = Bt + (size_t)(col0 + r) * K + k0off + (sw >> 1);
        ldstB[i] = idx * 8;
    }

    int offa[MFR], offb[NF];
    const int rsel = lane & 15, slot = lane >> 4;
    #pragma unroll
    for (int m = 0; m < MFR; ++m) {
        const int ra = wr * (BM / 2) + m * 16 + rsel;
        offa[m] = ra * 32 + (((slot << 4) ^ (((ra >> 1) & 3) << 4)) >> 1);
    }
    #pragma unroll
    for (int n = 0; n < NF; ++n) {
        const int rb = wc * (NF * 16) + n * 16 + rsel;
        offb[n] = rb * 32 + (((slot << 4) ^ (((rb >> 1) & 3) << 4)) >> 1);
    }

    floatx4 acc[MFR][NF] = {};

#define STAGE(AA, BB, t) do {                                   \
        const int ko_ = (t) << 5;                               \
        _Pragma("unroll")                                       \
        for (int i = 0; i < ALOADS; ++i)                        \
            GLDS(pa[i] + ko_, &AA[ldst[i]]);                    \
        _Pragma("unroll")                                       \
        for (int i = 0; i < BLOADS; ++i)                        \
            GLDS(pb[i] + ko_, &BB[ldstB[i]]);                   \
    } while (0)

#define COMPUTE(AA, BB) do {                                    \
        bf16x8 af[MFR], bfr[NF];                                \
        _Pragma("unroll")                                       \
        for (int m = 0; m < MFR; ++m) af[m] = *(const bf16x8*)&AA[offa[m]]; \
        _Pragma("unroll")                                       \
        for (int n = 0; n < NF; ++n) bfr[n] = *(const bf16x8*)&BB[offb[n]]; \
        _Pragma("unroll")                                       \
        for (int m = 0; m < MFR; ++m)                           \
            _Pragma("unroll")                                   \
            for (int n = 0; n < NF; ++n)                        \
                acc[m][n] = __builtin_amdgcn_mfma_f32_16x16x32_bf16( \
                        af[m], bfr[n], acc[m][n], 0, 0, 0);     \
    } while (0)

#define PHASE(CA, CB, NA, NB, t) do {                           \
        if ((t) < nkt - 1) {                                    \
            if constexpr (LOADS == 6)                           \
                asm volatile("s_waitcnt vmcnt(6)" ::: "memory");\
            else if constexpr (LOADS == 4)                      \
                asm volatile("s_waitcnt vmcnt(4)" ::: "memory");\
            else                                                \
                asm volatile("s_waitcnt vmcnt(3)" ::: "memory");\
        } else {                                                \
            asm volatile("s_waitcnt vmcnt(0)" ::: "memory");    \
        }                                                       \
        __builtin_amdgcn_s_barrier();                           \
        __builtin_amdgcn_sched_barrier(0);                      \
        if ((t) + 2 < nkt) STAGE(NA, NB, (t) + 2);              \
        COMPUTE(CA, CB);                                        \
    } while (0)

    const int nkt = Keff >> 5;       // 32, 64, 128
    STAGE(As0, Bs0, 0);
    STAGE(As1, Bs1, 1);
    int t = 0;
    for (; t + 3 <= nkt; t += 3) {
        PHASE(As0, Bs0, As2, Bs2, t);
        PHASE(As1, Bs1, As0, Bs0, t + 1);
        PHASE(As2, Bs2, As1, Bs1, t + 2);
    }
    if (t < nkt)     PHASE(As0, Bs0, As2, Bs2, t);
    if (t + 1 < nkt) PHASE(As1, Bs1, As0, Bs0, t + 1);
#undef STAGE
#undef COMPUTE
#undef PHASE

    const int cr4 = (lane >> 4) * 4;
    const int cc = lane & 15;

    if (EPI == 7) {
        float* dst = (blockIdx.z == 0) ? (float*)Cv : (float*)o1;
        const bool addb = (blockIdx.z == 0);
        #pragma unroll
        for (int n = 0; n < NF; ++n) {
            const int col = col0 + wc * (NF * 16) + n * 16 + cc;
            const float bv = addb ? bias[col] : 0.f;
            #pragma unroll
            for (int m = 0; m < MFR; ++m) {
                const int rowb = row0 + wr * (BM / 2) + m * 16 + cr4;
                #pragma unroll
                for (int r = 0; r < 4; ++r)
                    dst[(size_t)(rowb + r) * N + col] = acc[m][n][r] + bv;
            }
        }
        return;
    }

    if (EPI == 5 || EPI == 6) {
        const int seg = col0 >> 10;
        const int vtseg = (EPI == 5) ? 2 : 1;
        u16* dst;
        if (EPI == 5) dst = (seg == 0) ? (u16*)Cv : (seg == 1 ? o1 : o2);
        else          dst = (seg == 0) ? (u16*)Cv : o1;

        if (seg == vtseg) {
            #pragma unroll
            for (int n = 0; n < NF; ++n) {
                const int col = col0 + wc * (NF * 16) + n * 16 + cc;
                const float bv = bias[col];
                const int vcol = col & 1023;
                const int h = vcol >> 6, d = vcol & 63;
                #pragma unroll
                for (int m = 0; m < MFR; ++m) {
                    const int tk = row0 + wr * (BM / 2) + m * 16 + cr4;
                    const int b = tk >> 10;
                    ushort4 o4;
                    o4.x = f2bf(acc[m][n][0] + bv);
                    o4.y = f2bf(acc[m][n][1] + bv);
                    o4.z = f2bf(acc[m][n][2] + bv);
                    o4.w = f2bf(acc[m][n][3] + bv);
                    *(ushort4*)(dst +
                        (((size_t)(b * 16 + h) * 64 + d) * 1024 + (tk & 1023))) = o4;
                }
            }
        } else {
            const float osc = (EPI == 5 && seg == 0) ? SCLQ : 1.f;
            #pragma unroll
            for (int n = 0; n < NF; ++n) {
                const int col = col0 + wc * (NF * 16) + n * 16 + cc;
                const float bv = bias[col];
                const int oc = col & 1023;
                #pragma unroll
                for (int m = 0; m < MFR; ++m) {
                    const int rowb = row0 + wr * (BM / 2) + m * 16 + cr4;
                    #pragma unroll
                    for (int r = 0; r < 4; ++r)
                        dst[(size_t)(rowb + r) * 1024 + oc] = f2bf((acc[m][n][r] + bv) * osc);
                }
            }
        }
        return;
    }

    #pragma unroll
    for (int n = 0; n < NF; ++n) {
        const int col = col0 + wc * (NF * 16) + n * 16 + cc;
        const float bv = bias[col];
        #pragma unroll
        for (int m = 0; m < MFR; ++m) {
            const int rowb = row0 + wr * (BM / 2) + m * 16 + cr4;
            #pragma unroll
            for (int r = 0; r < 4; ++r) {
                float v = acc[m][n][r] + bv;
                const size_t o = (size_t)(rowb + r) * N + col;
                if (EPI == 2) v += u2f((unsigned)res[o] << 16);
                if (EPI == 1) v = fmaxf(v, 0.f);
                if (EPI == 8) v *= SCLQ;
                ((u16*)Cv)[o] = f2bf(v);
            }
        }
    }
}

// ---------------------------------------------------------------------------
// Fused prep: 10 weight transposes (f32->bf16, W[K,N] -> Wt[N,K]) +
// tgt/mem f32->bf16 conversion + bias concat, all in ONE dispatch.
// ---------------------------------------------------------------------------
struct PrepArgs {
    const float* w[10];
    u16* o[10];
    const float* tgt; const float* mem;
    u16* tgtb; u16* memb;
    const float* bq; const float* bk; const float* bv;
    const float* cbk; const float* cbv;
    float* biasQKV; float* biasKV;
};

__global__ __launch_bounds__(256) void prep_kernel(PrepArgs p)
{
    __shared__ float ts[64][65];
    const int tid = threadIdx.x;
    int bid = blockIdx.x;

    if (bid < 4096) {
        int w, n0, k0, K, N;
        if (bid < 2048) {
            w = bid >> 8;
            const int t = bid & 255;
            n0 = (t & 15) * 64; k0 = ((t >> 4) & 15) * 64; K = 1024; N = 1024;
        } else if (bid < 3072) {
            w = 8;
            const int t = bid - 2048;
            n0 = (t & 63) * 64; k0 = (t >> 6) * 64; K = 1024; N = 4096;
        } else {
            w = 9;
            const int t = bid - 3072;
            n0 = (t & 15) * 64; k0 = (t >> 4) * 64; K = 4096; N = 1024;
        }
        const float* __restrict__ W = p.w[w];
        u16* __restrict__ Wt = p.o[w];
        const int tr = tid >> 4, tc4 = (tid & 15) * 4;
        #pragma unroll
        for (int i = 0; i < 4; ++i) {
            const float4 v = *(const float4*)(W + (size_t)(k0 + tr + i * 16) * N + n0 + tc4);
            ts[tr + i * 16][tc4 + 0] = v.x;
            ts[tr + i * 16][tc4 + 1] = v.y;
            ts[tr + i * 16][tc4 + 2] = v.z;
            ts[tr + i * 16][tc4 + 3] = v.w;
        }
        __syncthreads();
        #pragma unroll
        for (int i = 0; i < 4; ++i) {
            const int nr = tr + i * 16;
            ushort4 o;
            o.x = f2bf(ts[tc4 + 0][nr]);
            o.y = f2bf(ts[tc4 + 1][nr]);
            o.z = f2bf(ts[tc4 + 2][nr]);
            o.w = f2bf(ts[tc4 + 3][nr]);
            *(ushort4*)(Wt + (size_t)(n0 + nr) * K + k0 + tc4) = o;
        }
        return;
    }
    bid -= 4096;
    if (bid < 4096) {
        const int i = bid * 256 + tid;
        const float4 v = ((const float4*)p.tgt)[i];
        ushort4 o;
        o.x = f2bf(v.x); o.y = f2bf(v.y); o.z = f2bf(v.z); o.w = f2bf(v.w);
        ((ushort4*)p.tgtb)[i] = o;
        return;
    }
    bid -= 4096;
    if (bid < 4096) {
        const int i = bid * 256 + tid;
        const float4 v = ((const float4*)p.mem)[i];
        ushort4 o;
        o.x = f2bf(v.x); o.y = f2bf(v.y); o.z = f2bf(v.z); o.w = f2bf(v.w);
        ((ushort4*)p.memb)[i] = o;
        return;
    }
    bid -= 4096;
    const int i = bid * 256 + tid;
    if (i < 3072)
        p.biasQKV[i] = (i < 1024) ? p.bq[i] : (i < 2048 ? p.bk[i - 1024] : p.bv[i - 2048]);
    if (i < 2048)
        p.biasKV[i] = (i < 1024) ? p.cbk[i] : p.cbv[i - 1024];
}

// ---------------------------------------------------------------------------
// MFMA flash attention, swapped-operand, STATIC-MAX softmax.
// Q pre-scaled by 0.125*log2(e) upstream; P = exp2(s) directly.
// Grid (64, 16). LDS 24 KB.
// ---------------------------------------------------------------------------
template<int CAUSAL>
__global__ __launch_bounds__(256) void fattn_mfma(
        const u16* __restrict__ Q, const u16* __restrict__ K,
        const u16* __restrict__ Vt, u16* __restrict__ O)
{
    __shared__ u16 Ks[64 * 64];
    __shared__ u16 Vs[64 * 64];
    __shared__ u16 Ps[64 * 64];

    const int tid = threadIdx.x;
    const int lane = tid & 63, wv = tid >> 6;
    const int g = lane >> 4, qx = lane & 15;
    const int bh = blockIdx.x;
    const int b = bh >> 4, h = bh & 15;
    const int qt = blockIdx.y, q0 = qt * 64;

    const size_t qkbase = (size_t)b * (1024 * 1024) + (size_t)h * 64;
    const size_t vtbase = (size_t)bh * 64 * 1024;

    const int qr = wv * 16 + qx;
    const int qg = q0 + qr;
    const int swzq = (qr & 7) << 4;

    bf16x8 qf[2];
    #pragma unroll
    for (int ks = 0; ks < 2; ++ks)
        qf[ks] = *(const bf16x8*)(Q + qkbase + (size_t)qg * 1024 + ks * 32 + g * 8);

    const int r0 = tid >> 3, s0 = tid & 7;

    float l_i = 0.f;
    floatx4 o_acc[4] = {};

    const int ktmax = CAUSAL ? qt : 15;
    for (int kt = 0; kt <= ktmax; ++kt) {
        __syncthreads();
        #pragma unroll
        for (int i = 0; i < 2; ++i) {
            const int r = i * 32 + r0;
            const uint4 kv = *(const uint4*)(K + qkbase + (size_t)(kt * 64 + r) * 1024 + s0 * 8);
            *(uint4*)((char*)Ks + r * 128 + ((s0 ^ (r & 7)) << 4)) = kv;
            const uint4 vv = *(const uint4*)(Vt + vtbase + (size_t)r * 1024 + kt * 64 + s0 * 8);
            *(uint4*)((char*)Vs + r * 128 + ((s0 ^ (r & 7)) << 4)) = vv;
        }
        __syncthreads();

        floatx4 sa[4] = {};
        #pragma unroll
        for (int ks = 0; ks < 2; ++ks) {
            #pragma unroll
            for (int m = 0; m < 4; ++m) {
                const int rr = m * 16 + qx;
                const int sl = ks * 4 + g;
                const bf16x8 kf = *(const bf16x8*)((char*)Ks + rr * 128 + ((sl ^ (rr & 7)) << 4));
                sa[m] = __builtin_amdgcn_mfma_f32_16x16x32_bf16(kf, qf[ks], sa[m], 0, 0, 0);
            }
        }

        float p[4][4];
        float rs = 0.f;
        #pragma unroll
        for (int m = 0; m < 4; ++m)
            #pragma unroll
            for (int r = 0; r < 4; ++r) {
                float e = exp2f(sa[m][r]);
                if (CAUSAL && kt == qt) {
                    const int kl = m * 16 + g * 4 + r;
                    if (kl > qr) e = 0.f;
                }
                p[m][r] = e;
                rs += e;
            }
        rs += __shfl_xor(rs, 16);
        rs += __shfl_xor(rs, 32);
        l_i += rs;

        #pragma unroll
        for (int m = 0; m < 4; ++m) {
            uint2 pk;
            pk.x = pk2bf(p[m][0], p[m][1]);
            pk.y = pk2bf(p[m][2], p[m][3]);
            *(uint2*)((char*)Ps + qr * 128 + ((m * 32 + g * 8) ^ swzq)) = pk;
        }

        #pragma unroll
        for (int ks2 = 0; ks2 < 2; ++ks2) {
            const bf16x8 pf = *(const bf16x8*)((char*)Ps + qr * 128 + ((ks2 * 64 + g * 16) ^ swzq));
            #pragma unroll
            for (int n = 0; n < 4; ++n) {
                const int rv = n * 16 + qx;
                const int sl = ks2 * 4 + g;
                const bf16x8 vf = *(const bf16x8*)((char*)Vs + rv * 128 + ((sl ^ (rv & 7)) << 4));
                o_acc[n] = __builtin_amdgcn_mfma_f32_16x16x32_bf16(vf, pf, o_acc[n], 0, 0, 0);
            }
        }
    }

    const float inv = 1.f / l_i;
    #pragma unroll
    for (int n = 0; n < 4; ++n) {
        uint2 ov;
        ov.x = pk2bf(o_acc[n][0] * inv, o_acc[n][1] * inv);
        ov.y = pk2bf(o_acc[n][2] * inv, o_acc[n][3] * inv);
        *(uint2*)((char*)Ps + qr * 128 + ((n * 32 + g * 8) ^ swzq)) = ov;
    }
    const int orow = wv * 16 + (lane >> 2);
    const int swzo = (orow & 7) << 4;
    #pragma unroll
    for (int i = 0; i < 2; ++i) {
        const int cb = ((lane & 3) * 2 + i) * 16;
        const uint4 ov = *(const uint4*)((char*)Ps + orow * 128 + (cb ^ swzo));
        *(uint4*)(O + qkbase + (size_t)(q0 + orow) * 1024 + cb / 2) = ov;
    }
}

// ---------------------------------------------------------------------------
// LayerNorm, bf16 in/out, fp32 stats. One block (256) per row of 1024.
// ---------------------------------------------------------------------------
__global__ __launch_bounds__(256) void ln_bf16_kernel(
        const u16* __restrict__ X, const float* __restrict__ g,
        const float* __restrict__ bta, u16* __restrict__ Y)
{
    __shared__ float red[4];
    const int row = blockIdx.x, tid = threadIdx.x;
    const int wave = tid >> 6, lane = tid & 63;

    const uint2 u = *(const uint2*)(X + (size_t)row * 1024 + tid * 4);
    const float x0 = bflo(u.x), x1 = bfhi(u.x), x2 = bflo(u.y), x3 = bfhi(u.y);

    float s = x0 + x1 + x2 + x3;
    #pragma unroll
    for (int off = 32; off; off >>= 1) s += __shfl_xor(s, off);
    if (lane == 0) red[wave] = s;
    __syncthreads();
    const float mu = (red[0] + red[1] + red[2] + red[3]) * (1.f / 1024.f);
    __syncthreads();

    const float d0 = x0 - mu, d1 = x1 - mu, d2 = x2 - mu, d3 = x3 - mu;
    float s2 = d0 * d0 + d1 * d1 + d2 * d2 + d3 * d3;
    #pragma unroll
    for (int off = 32; off; off >>= 1) s2 += __shfl_xor(s2, off);
    if (lane == 0) red[wave] = s2;
    __syncthreads();
    const float var = (red[0] + red[1] + red[2] + red[3]) * (1.f / 1024.f);
    const float rs = rsqrtf(var + 1e-5f);

    const float4 gg = ((const float4*)g)[tid];
    const float4 bb = ((const float4*)bta)[tid];
    ushort4 o;
    o.x = f2bf(d0 * rs * gg.x + bb.x);
    o.y = f2bf(d1 * rs * gg.y + bb.y);
    o.z = f2bf(d2 * rs * gg.z + bb.z);
    o.w = f2bf(d3 * rs * gg.w + bb.w);
    *(ushort4*)(Y + (size_t)row * 1024 + tid * 4) = o;
}

// final LayerNorm: X0 + X1 (f32 split-K partials) + bf16 residual -> f32 out
__global__ __launch_bounds__(256) void ln_res_kernel(
        const float* X0, const float* __restrict__ X1,
        const u16* __restrict__ res, const float* __restrict__ g,
        const float* __restrict__ bta, float* Y)
{
    __shared__ float red[4];
    const int row = blockIdx.x;
    const int tid = threadIdx.x;
    const int wave = tid >> 6, lane = tid & 63;

    const float4 v0 = ((const float4*)(X0 + (size_t)row * 1024))[tid];
    const float4 v1 = ((const float4*)(X1 + (size_t)row * 1024))[tid];
    const uint2 u = *(const uint2*)(res + (size_t)row * 1024 + tid * 4);
    const float x0 = v0.x + v1.x + bflo(u.x), x1 = v0.y + v1.y + bfhi(u.x);
    const float x2 = v0.z + v1.z + bflo(u.y), x3 = v0.w + v1.w + bfhi(u.y);

    float s = x0 + x1 + x2 + x3;
    #pragma unroll
    for (int off = 32; off; off >>= 1) s += __shfl_xor(s, off);
    if (lane == 0) red[wave] = s;
    __syncthreads();
    const float mu = (red[0] + red[1] + red[2] + red[3]) * (1.f / 1024.f);
    __syncthreads();

    const float d0 = x0 - mu, d1 = x1 - mu, d2 = x2 - mu, d3 = x3 - mu;
    float s2 = d0 * d0 + d1 * d1 + d2 * d2 + d3 * d3;
    #pragma unroll
    for (int off = 32; off; off >>= 1) s2 += __shfl_xor(s2, off);
    if (lane == 0) red[wave] = s2;
    __syncthreads();
    const float var = (red[0] + red[1] + red[2] + red[3]) * (1.f / 1024.f);
    const float rs = rsqrtf(var + 1e-5f);

    const float4 gg = ((const float4*)g)[tid];
    const float4 bb = ((const float4*)bta)[tid];
    float4 o;
    o.x = d0 * rs * gg.x + bb.x;
    o.y = d1 * rs * gg.y + bb.y;
    o.z = d2 * rs * gg.z + bb.z;
    o.w = d3 * rs * gg.w + bb.w;
    ((float4*)(Y + (size_t)row * 1024))[tid] = o;
}

// ---------------------------------------------------------------------------
extern "C" void kernel_launch(void* const* d_in, const int* in_sizes, int n_in,
                              void* d_out, int out_size, void* d_ws, size_t ws_size,
                              hipStream_t stream)
{
    const float* tgt    = (const float*)d_in[0];
    const float* mem    = (const float*)d_in[1];
    const float* sa_wq  = (const float*)d_in[3];
    const float* sa_bq  = (const float*)d_in[4];
    const float* sa_wk  = (const float*)d_in[5];
    const float* sa_bk  = (const float*)d_in[6];
    const float* sa_wv  = (const float*)d_in[7];
    const float* sa_bv  = (const float*)d_in[8];
    const float* sa_wo  = (const float*)d_in[9];
    const float* sa_bo  = (const float*)d_in[10];
    const float* ca_wq  = (const float*)d_in[11];
    const float* ca_bq  = (const float*)d_in[12];
    const float* ca_wk  = (const float*)d_in[13];
    const float* ca_bk  = (const float*)d_in[14];
    const float* ca_wv  = (const float*)d_in[15];
    const float* ca_bv  = (const float*)d_in[16];
    const float* ca_wo  = (const float*)d_in[17];
    const float* ca_bo  = (const float*)d_in[18];
    const float* ffn_w1 = (const float*)d_in[19];
    const float* ffn_b1 = (const float*)d_in[20];
    const float* ffn_w2 = (const float*)d_in[21];
    const float* ffn_b2 = (const float*)d_in[22];
    const float* ln1_g  = (const float*)d_in[23];
    const float* ln1_b  = (const float*)d_in[24];
    const float* ln2_g  = (const float*)d_in[25];
    const float* ln2_b  = (const float*)d_in[26];
    const float* ln3_g  = (const float*)d_in[27];
    const float* ln3_b  = (const float*)d_in[28];

    float* out = (float*)d_out;
    u16* wsb = (u16*)d_ws;
    const size_t M1 = 1024 * 1024;

    u16* Wsq = wsb + 0 * M1;
    u16* Wsk = wsb + 1 * M1;
    u16* Wsv = wsb + 2 * M1;
    u16* Wso = wsb + 3 * M1;
    u16* Wcq = wsb + 4 * M1;
    u16* Wck = wsb + 5 * M1;
    u16* Wcv = wsb + 6 * M1;
    u16* Wco = wsb + 7 * M1;
    u16* Wf1 = wsb + 8 * M1;
    u16* Wf2 = wsb + 12 * M1;

    u16* sl = wsb + 16 * M1;
    u16* s0 = sl + 0 * 4 * M1;
    u16* s1 = sl + 4 * M1;
    u16* s2 = sl + 8 * M1;
    u16* s3 = sl + 12 * M1;
    u16* s4 = sl + 16 * M1;
    u16* s5 = sl + 20 * M1;
    u16* H  = s0;

    float* part1 = (float*)wsb;

    float* biasQKV = (float*)(wsb + 40 * M1);
    float* biasKV  = biasQKV + 3072;

    const dim3 blk(256);
    const dim3 gqkv(24, 32);
    const dim3 gkv(16, 32);
    const dim3 g1(16, 32);
    const dim3 g4(32, 16);
    const dim3 gf2(8, 32, 2);
    const dim3 ga(64, 16);
    const dim3 gln(4096);

    PrepArgs pa;
    pa.w[0] = sa_wq; pa.o[0] = Wsq;
    pa.w[1] = sa_wk; pa.o[1] = Wsk;
    pa.w[2] = sa_wv; pa.o[2] = Wsv;
    pa.w[3] = sa_wo; pa.o[3] = Wso;
    pa.w[4] = ca_wq; pa.o[4] = Wcq;
    pa.w[5] = ca_wk; pa.o[5] = Wck;
    pa.w[6] = ca_wv; pa.o[6] = Wcv;
    pa.w[7] = ca_wo; pa.o[7] = Wco;
    pa.w[8] = ffn_w1; pa.o[8] = Wf1;
    pa.w[9] = ffn_w2; pa.o[9] = Wf2;
    pa.tgt = tgt; pa.mem = mem; pa.tgtb = s0; pa.memb = s1;
    pa.bq = sa_bq; pa.bk = sa_bk; pa.bv = sa_bv;
    pa.cbk = ca_bk; pa.cbv = ca_bv;
    pa.biasQKV = biasQKV; pa.biasKV = biasKV;
    prep_kernel<<<12308, blk, 0, stream>>>(pa);

    // ---- self-attention ----
    gemm_mfma<5, 4, 4><<<gqkv, blk, 0, stream>>>(s0, Wsq, biasQKV, nullptr,
                                                 s2, s3, s4, 3072, 1024);
    fattn_mfma<1><<<ga, blk, 0, stream>>>(s2, s3, s4, s5);
    gemm_mfma<2, 2, 4><<<g1, blk, 0, stream>>>(s5, Wso, sa_bo, s0, s2, nullptr, nullptr, 1024, 1024);
    ln_bf16_kernel<<<gln, blk, 0, stream>>>(s2, ln1_g, ln1_b, s3);

    // ---- cross-attention ----
    gemm_mfma<8, 2, 4><<<g1, blk, 0, stream>>>(s3, Wcq, ca_bq, nullptr, s2, nullptr, nullptr, 1024, 1024);
    gemm_mfma<6, 4, 4><<<gkv, blk, 0, stream>>>(s1, Wck, biasKV, nullptr,
                                                s4, s5, nullptr, 2048, 1024);
    fattn_mfma<0><<<ga, blk, 0, stream>>>(s2, s4, s5, s0);
    gemm_mfma<2, 2, 4><<<g1, blk, 0, stream>>>(s0, Wco, ca_bo, s3, s2, nullptr, nullptr, 1024, 1024);
    ln_bf16_kernel<<<gln, blk, 0, stream>>>(s2, ln2_g, ln2_b, s4);

    // ---- FFN ----
    gemm_mfma<1, 4, 8><<<g4, blk, 0, stream>>>(s4, Wf1, ffn_b1, nullptr, H, nullptr, nullptr, 4096, 1024);
    gemm_mfma<7, 4, 4><<<gf2, blk, 0, stream>>>(H, Wf2, ffn_b2, nullptr, out,
                                                (u16*)part1, nullptr, 1024, 4096);
    ln_res_kernel<<<gln, blk, 0, stream>>>(out, part1, s4, ln3_g, ln3_b, out);
}

// Round 20
// 310.633 us; speedup vs baseline: 1.0826x; 1.0251x over previous
//
#include <hip/hip_runtime.h>
#include <hip/hip_bf16.h>

typedef unsigned short u16;
typedef __attribute__((ext_vector_type(8))) short bf16x8;
typedef __attribute__((ext_vector_type(4))) float floatx4;

__device__ inline float u2f(unsigned u) { union { unsigned i; float f; } x; x.i = u; return x.f; }
__device__ inline float bflo(unsigned p) { return u2f(p << 16); }
__device__ inline float bfhi(unsigned p) { return u2f(p & 0xffff0000u); }
__device__ inline u16 f2bf(float f) {
    union { __hip_bfloat16 h; u16 u; } x;
    x.h = __float2bfloat16(f);
    return x.u;
}
__device__ inline unsigned pk2bf(float lo, float hi) {
    return ((unsigned)f2bf(hi) << 16) | f2bf(lo);
}

#define SCLQ 0.18033688011f   // 0.125 * log2(e), folded into Q

#define GLDS(g, l) __builtin_amdgcn_global_load_lds( \
    (const __attribute__((address_space(1))) void*)(g), \
    (__attribute__((address_space(3))) void*)(l), 16, 0, 0)

// ---------------------------------------------------------------------------
// bf16 MFMA GEMM: C[M,N] = A[M,K] @ Bt[N,K]^T + bias (+res) (+relu)
// Block tile (MW*32) x (NF*32), 4 waves (2x2), 16x16x32 MFMA, BK=32,
// XCD-chunked swizzle, 3-buffer counted-vmcnt pipeline (stage t+2, steady
// wait vmcnt(LOADS), drain only on last tile).
//   MW=4: 128-row block;  MW=8: 256-row block (FFN1, better MFMA:ds ratio).
// EPI: 0 bf16, 1 +relu, 2 +bf16 res,
//      5 seg QKV (seg0 Q*SCLQ -> Cv, seg1 K -> o1, seg2 Vt -> o2),
//      6 seg KV (seg0 K -> Cv, seg1 Vt -> o1),
//      7 split-K f32 partials (z0 -> Cv +bias, z1 -> o1), 8 bf16 * SCLQ,
//      9 = EPI 5 with per-segment A: seg0 reads A (x1), seg1/2 read A2 (mem).
// Vt layout: Vt[b*16+h][d][t], t fast.
// ---------------------------------------------------------------------------
template<int EPI, int NF, int MW>
__global__ __launch_bounds__(256, (MW == 8) ? 2 : 3) void gemm_mfma(
        const u16* __restrict__ A, const u16* __restrict__ Bt,
        const float* __restrict__ bias, const u16* __restrict__ res,
        void* __restrict__ Cv, u16* __restrict__ o1, u16* __restrict__ o2,
        const u16* __restrict__ A2, int N, int K)
{
    constexpr int BN = NF * 32;
    constexpr int BM = MW * 32;
    constexpr int MFR = BM / 32;
    constexpr int ALOADS = BM / 64;
    constexpr int BLOADS = BN / 64;
    constexpr int LOADS = ALOADS + BLOADS;

    __shared__ u16 As0[BM * 32];
    __shared__ u16 Bs0[BN * 32];
    __shared__ u16 As1[BM * 32];
    __shared__ u16 Bs1[BN * 32];
    __shared__ u16 As2[BM * 32];
    __shared__ u16 Bs2[BN * 32];

    const int tid = threadIdx.x;
    const int lane = tid & 63, wv = tid >> 6;
    const int wr = wv >> 1, wc = wv & 1;

    const int gx = gridDim.x;
    const int nwg = gx * gridDim.y;
    const int bid0 = blockIdx.y * gx + blockIdx.x;
    const int nbid = (bid0 & 7) * (nwg >> 3) + (bid0 >> 3);
    const int bx = nbid % gx, by = nbid / gx;
    const int row0 = by * BM, col0 = bx * BN;

    const int Keff = (EPI == 7) ? (K >> 1) : K;
    const int k0off = (EPI == 7) ? blockIdx.z * Keff : 0;

    // EPI 9: per-segment A source (block-uniform; 1024 % BN == 0)
    const u16* Abase = (EPI == 9 && col0 >= 1024) ? A2 : A;

    const u16* pa[ALOADS];
    int ldst[ALOADS];
    #pragma unroll
    for (int i = 0; i < ALOADS; ++i) {
        const int idx = i * 256 + tid;
        const int r = idx >> 2;
        const int kob = (idx & 3) << 4;
        const int sw = kob ^ (((r >> 1) & 3) << 4);
        pa[i] = Abase + (size_t)(row0 + r) * K + k0off + (sw >> 1);
        ldst[i] = idx * 8;
    }
    const u16* pb[BLOADS];
    int ldstB[BLOADS];
    #pragma unroll
    for (int i = 0; i < BLOADS; ++i) {
        const int idx = i * 256 + tid;
        const int r = idx >> 2;
        const int kob = (idx & 3) << 4;
        const int sw = kob ^ (((r >> 1) & 3) << 4);
        pb[i] = Bt + (size_t)(col0 + r) * K + k0off + (sw >> 1);
        ldstB[i] = idx * 8;
    }

    int offa[MFR], offb[NF];
    const int rsel = lane & 15, slot = lane >> 4;
    #pragma unroll
    for (int m = 0; m < MFR; ++m) {
        const int ra = wr * (BM / 2) + m * 16 + rsel;
        offa[m] = ra * 32 + (((slot << 4) ^ (((ra >> 1) & 3) << 4)) >> 1);
    }
    #pragma unroll
    for (int n = 0; n < NF; ++n) {
        const int rb = wc * (NF * 16) + n * 16 + rsel;
        offb[n] = rb * 32 + (((slot << 4) ^ (((rb >> 1) & 3) << 4)) >> 1);
    }

    floatx4 acc[MFR][NF] = {};

#define STAGE(AA, BB, t) do {                                   \
        const int ko_ = (t) << 5;                               \
        _Pragma("unroll")                                       \
        for (int i = 0; i < ALOADS; ++i)                        \
            GLDS(pa[i] + ko_, &AA[ldst[i]]);                    \
        _Pragma("unroll")                                       \
        for (int i = 0; i < BLOADS; ++i)                        \
            GLDS(pb[i] + ko_, &BB[ldstB[i]]);                   \
    } while (0)

#define COMPUTE(AA, BB) do {                                    \
        bf16x8 af[MFR], bfr[NF];                                \
        _Pragma("unroll")                                       \
        for (int m = 0; m < MFR; ++m) af[m] = *(const bf16x8*)&AA[offa[m]]; \
        _Pragma("unroll")                                       \
        for (int n = 0; n < NF; ++n) bfr[n] = *(const bf16x8*)&BB[offb[n]]; \
        _Pragma("unroll")                                       \
        for (int m = 0; m < MFR; ++m)                           \
            _Pragma("unroll")                                   \
            for (int n = 0; n < NF; ++n)                        \
                acc[m][n] = __builtin_amdgcn_mfma_f32_16x16x32_bf16( \
                        af[m], bfr[n], acc[m][n], 0, 0, 0);     \
    } while (0)

#define PHASE(CA, CB, NA, NB, t) do {                           \
        if ((t) < nkt - 1) {                                    \
            if constexpr (LOADS == 6)                           \
                asm volatile("s_waitcnt vmcnt(6)" ::: "memory");\
            else if constexpr (LOADS == 4)                      \
                asm volatile("s_waitcnt vmcnt(4)" ::: "memory");\
            else                                                \
                asm volatile("s_waitcnt vmcnt(3)" ::: "memory");\
        } else {                                                \
            asm volatile("s_waitcnt vmcnt(0)" ::: "memory");    \
        }                                                       \
        __builtin_amdgcn_s_barrier();                           \
        __builtin_amdgcn_sched_barrier(0);                      \
        if ((t) + 2 < nkt) STAGE(NA, NB, (t) + 2);              \
        COMPUTE(CA, CB);                                        \
    } while (0)

    const int nkt = Keff >> 5;       // 32, 64, 128
    STAGE(As0, Bs0, 0);
    STAGE(As1, Bs1, 1);
    int t = 0;
    for (; t + 3 <= nkt; t += 3) {
        PHASE(As0, Bs0, As2, Bs2, t);
        PHASE(As1, Bs1, As0, Bs0, t + 1);
        PHASE(As2, Bs2, As1, Bs1, t + 2);
    }
    if (t < nkt)     PHASE(As0, Bs0, As2, Bs2, t);
    if (t + 1 < nkt) PHASE(As1, Bs1, As0, Bs0, t + 1);
#undef STAGE
#undef COMPUTE
#undef PHASE

    const int cr4 = (lane >> 4) * 4;
    const int cc = lane & 15;

    if (EPI == 7) {
        float* dst = (blockIdx.z == 0) ? (float*)Cv : (float*)o1;
        const bool addb = (blockIdx.z == 0);
        #pragma unroll
        for (int n = 0; n < NF; ++n) {
            const int col = col0 + wc * (NF * 16) + n * 16 + cc;
            const float bv = addb ? bias[col] : 0.f;
            #pragma unroll
            for (int m = 0; m < MFR; ++m) {
                const int rowb = row0 + wr * (BM / 2) + m * 16 + cr4;
                #pragma unroll
                for (int r = 0; r < 4; ++r)
                    dst[(size_t)(rowb + r) * N + col] = acc[m][n][r] + bv;
            }
        }
        return;
    }

    if (EPI == 5 || EPI == 6 || EPI == 9) {
        const int seg = col0 >> 10;
        const int vtseg = (EPI == 6) ? 1 : 2;
        u16* dst;
        if (EPI == 6) dst = (seg == 0) ? (u16*)Cv : o1;
        else          dst = (seg == 0) ? (u16*)Cv : (seg == 1 ? o1 : o2);

        if (seg == vtseg) {
            #pragma unroll
            for (int n = 0; n < NF; ++n) {
                const int col = col0 + wc * (NF * 16) + n * 16 + cc;
                const float bv = bias[col];
                const int vcol = col & 1023;
                const int h = vcol >> 6, d = vcol & 63;
                #pragma unroll
                for (int m = 0; m < MFR; ++m) {
                    const int tk = row0 + wr * (BM / 2) + m * 16 + cr4;
                    const int b = tk >> 10;
                    ushort4 o4;
                    o4.x = f2bf(acc[m][n][0] + bv);
                    o4.y = f2bf(acc[m][n][1] + bv);
                    o4.z = f2bf(acc[m][n][2] + bv);
                    o4.w = f2bf(acc[m][n][3] + bv);
                    *(ushort4*)(dst +
                        (((size_t)(b * 16 + h) * 64 + d) * 1024 + (tk & 1023))) = o4;
                }
            }
        } else {
            const float osc = ((EPI == 5 || EPI == 9) && seg == 0) ? SCLQ : 1.f;
            #pragma unroll
            for (int n = 0; n < NF; ++n) {
                const int col = col0 + wc * (NF * 16) + n * 16 + cc;
                const float bv = bias[col];
                const int oc = col & 1023;
                #pragma unroll
                for (int m = 0; m < MFR; ++m) {
                    const int rowb = row0 + wr * (BM / 2) + m * 16 + cr4;
                    #pragma unroll
                    for (int r = 0; r < 4; ++r)
                        dst[(size_t)(rowb + r) * 1024 + oc] = f2bf((acc[m][n][r] + bv) * osc);
                }
            }
        }
        return;
    }

    #pragma unroll
    for (int n = 0; n < NF; ++n) {
        const int col = col0 + wc * (NF * 16) + n * 16 + cc;
        const float bv = bias[col];
        #pragma unroll
        for (int m = 0; m < MFR; ++m) {
            const int rowb = row0 + wr * (BM / 2) + m * 16 + cr4;
            #pragma unroll
            for (int r = 0; r < 4; ++r) {
                float v = acc[m][n][r] + bv;
                const size_t o = (size_t)(rowb + r) * N + col;
                if (EPI == 2) v += u2f((unsigned)res[o] << 16);
                if (EPI == 1) v = fmaxf(v, 0.f);
                if (EPI == 8) v *= SCLQ;
                ((u16*)Cv)[o] = f2bf(v);
            }
        }
    }
}

// ---------------------------------------------------------------------------
// Fused prep: 10 weight transposes (f32->bf16, W[K,N] -> Wt[N,K]) +
// tgt/mem f32->bf16 conversion + bias concat, all in ONE dispatch.
// ---------------------------------------------------------------------------
struct PrepArgs {
    const float* w[10];
    u16* o[10];
    const float* tgt; const float* mem;
    u16* tgtb; u16* memb;
    const float* bq; const float* bk; const float* bv;      // sa biases
    const float* cbq; const float* cbk; const float* cbv;   // ca biases
    float* biasQKV; float* biasCA;
};

__global__ __launch_bounds__(256) void prep_kernel(PrepArgs p)
{
    __shared__ float ts[64][65];
    const int tid = threadIdx.x;
    int bid = blockIdx.x;

    if (bid < 4096) {
        int w, n0, k0, K, N;
        if (bid < 2048) {
            w = bid >> 8;
            const int t = bid & 255;
            n0 = (t & 15) * 64; k0 = ((t >> 4) & 15) * 64; K = 1024; N = 1024;
        } else if (bid < 3072) {
            w = 8;
            const int t = bid - 2048;
            n0 = (t & 63) * 64; k0 = (t >> 6) * 64; K = 1024; N = 4096;
        } else {
            w = 9;
            const int t = bid - 3072;
            n0 = (t & 15) * 64; k0 = (t >> 4) * 64; K = 4096; N = 1024;
        }
        const float* __restrict__ W = p.w[w];
        u16* __restrict__ Wt = p.o[w];
        const int tr = tid >> 4, tc4 = (tid & 15) * 4;
        #pragma unroll
        for (int i = 0; i < 4; ++i) {
            const float4 v = *(const float4*)(W + (size_t)(k0 + tr + i * 16) * N + n0 + tc4);
            ts[tr + i * 16][tc4 + 0] = v.x;
            ts[tr + i * 16][tc4 + 1] = v.y;
            ts[tr + i * 16][tc4 + 2] = v.z;
            ts[tr + i * 16][tc4 + 3] = v.w;
        }
        __syncthreads();
        #pragma unroll
        for (int i = 0; i < 4; ++i) {
            const int nr = tr + i * 16;
            ushort4 o;
            o.x = f2bf(ts[tc4 + 0][nr]);
            o.y = f2bf(ts[tc4 + 1][nr]);
            o.z = f2bf(ts[tc4 + 2][nr]);
            o.w = f2bf(ts[tc4 + 3][nr]);
            *(ushort4*)(Wt + (size_t)(n0 + nr) * K + k0 + tc4) = o;
        }
        return;
    }
    bid -= 4096;
    if (bid < 4096) {
        const int i = bid * 256 + tid;
        const float4 v = ((const float4*)p.tgt)[i];
        ushort4 o;
        o.x = f2bf(v.x); o.y = f2bf(v.y); o.z = f2bf(v.z); o.w = f2bf(v.w);
        ((ushort4*)p.tgtb)[i] = o;
        return;
    }
    bid -= 4096;
    if (bid < 4096) {
        const int i = bid * 256 + tid;
        const float4 v = ((const float4*)p.mem)[i];
        ushort4 o;
        o.x = f2bf(v.x); o.y = f2bf(v.y); o.z = f2bf(v.z); o.w = f2bf(v.w);
        ((ushort4*)p.memb)[i] = o;
        return;
    }
    bid -= 4096;
    const int i = bid * 256 + tid;
    if (i < 3072) {
        p.biasQKV[i] = (i < 1024) ? p.bq[i] : (i < 2048 ? p.bk[i - 1024] : p.bv[i - 2048]);
        p.biasCA[i]  = (i < 1024) ? p.cbq[i] : (i < 2048 ? p.cbk[i - 1024] : p.cbv[i - 2048]);
    }
}

// ---------------------------------------------------------------------------
// MFMA flash attention, swapped-operand, STATIC-MAX softmax.
// Q pre-scaled by 0.125*log2(e) upstream; P = exp2(s) directly.
// Grid (64, 16). LDS 24 KB.
// ---------------------------------------------------------------------------
template<int CAUSAL>
__global__ __launch_bounds__(256) void fattn_mfma(
        const u16* __restrict__ Q, const u16* __restrict__ K,
        const u16* __restrict__ Vt, u16* __restrict__ O)
{
    __shared__ u16 Ks[64 * 64];
    __shared__ u16 Vs[64 * 64];
    __shared__ u16 Ps[64 * 64];

    const int tid = threadIdx.x;
    const int lane = tid & 63, wv = tid >> 6;
    const int g = lane >> 4, qx = lane & 15;
    const int bh = blockIdx.x;
    const int b = bh >> 4, h = bh & 15;
    const int qt = blockIdx.y, q0 = qt * 64;

    const size_t qkbase = (size_t)b * (1024 * 1024) + (size_t)h * 64;
    const size_t vtbase = (size_t)bh * 64 * 1024;

    const int qr = wv * 16 + qx;
    const int qg = q0 + qr;
    const int swzq = (qr & 7) << 4;

    bf16x8 qf[2];
    #pragma unroll
    for (int ks = 0; ks < 2; ++ks)
        qf[ks] = *(const bf16x8*)(Q + qkbase + (size_t)qg * 1024 + ks * 32 + g * 8);

    const int r0 = tid >> 3, s0 = tid & 7;

    float l_i = 0.f;
    floatx4 o_acc[4] = {};

    const int ktmax = CAUSAL ? qt : 15;
    for (int kt = 0; kt <= ktmax; ++kt) {
        __syncthreads();
        #pragma unroll
        for (int i = 0; i < 2; ++i) {
            const int r = i * 32 + r0;
            const uint4 kv = *(const uint4*)(K + qkbase + (size_t)(kt * 64 + r) * 1024 + s0 * 8);
            *(uint4*)((char*)Ks + r * 128 + ((s0 ^ (r & 7)) << 4)) = kv;
            const uint4 vv = *(const uint4*)(Vt + vtbase + (size_t)r * 1024 + kt * 64 + s0 * 8);
            *(uint4*)((char*)Vs + r * 128 + ((s0 ^ (r & 7)) << 4)) = vv;
        }
        __syncthreads();

        floatx4 sa[4] = {};
        #pragma unroll
        for (int ks = 0; ks < 2; ++ks) {
            #pragma unroll
            for (int m = 0; m < 4; ++m) {
                const int rr = m * 16 + qx;
                const int sl = ks * 4 + g;
                const bf16x8 kf = *(const bf16x8*)((char*)Ks + rr * 128 + ((sl ^ (rr & 7)) << 4));
                sa[m] = __builtin_amdgcn_mfma_f32_16x16x32_bf16(kf, qf[ks], sa[m], 0, 0, 0);
            }
        }

        float p[4][4];
        float rs = 0.f;
        #pragma unroll
        for (int m = 0; m < 4; ++m)
            #pragma unroll
            for (int r = 0; r < 4; ++r) {
                float e = exp2f(sa[m][r]);
                if (CAUSAL && kt == qt) {
                    const int kl = m * 16 + g * 4 + r;
                    if (kl > qr) e = 0.f;
                }
                p[m][r] = e;
                rs += e;
            }
        rs += __shfl_xor(rs, 16);
        rs += __shfl_xor(rs, 32);
        l_i += rs;

        #pragma unroll
        for (int m = 0; m < 4; ++m) {
            uint2 pk;
            pk.x = pk2bf(p[m][0], p[m][1]);
            pk.y = pk2bf(p[m][2], p[m][3]);
            *(uint2*)((char*)Ps + qr * 128 + ((m * 32 + g * 8) ^ swzq)) = pk;
        }

        #pragma unroll
        for (int ks2 = 0; ks2 < 2; ++ks2) {
            const bf16x8 pf = *(const bf16x8*)((char*)Ps + qr * 128 + ((ks2 * 64 + g * 16) ^ swzq));
            #pragma unroll
            for (int n = 0; n < 4; ++n) {
                const int rv = n * 16 + qx;
                const int sl = ks2 * 4 + g;
                const bf16x8 vf = *(const bf16x8*)((char*)Vs + rv * 128 + ((sl ^ (rv & 7)) << 4));
                o_acc[n] = __builtin_amdgcn_mfma_f32_16x16x32_bf16(vf, pf, o_acc[n], 0, 0, 0);
            }
        }
    }

    const float inv = 1.f / l_i;
    #pragma unroll
    for (int n = 0; n < 4; ++n) {
        uint2 ov;
        ov.x = pk2bf(o_acc[n][0] * inv, o_acc[n][1] * inv);
        ov.y = pk2bf(o_acc[n][2] * inv, o_acc[n][3] * inv);
        *(uint2*)((char*)Ps + qr * 128 + ((n * 32 + g * 8) ^ swzq)) = ov;
    }
    const int orow = wv * 16 + (lane >> 2);
    const int swzo = (orow & 7) << 4;
    #pragma unroll
    for (int i = 0; i < 2; ++i) {
        const int cb = ((lane & 3) * 2 + i) * 16;
        const uint4 ov = *(const uint4*)((char*)Ps + orow * 128 + (cb ^ swzo));
        *(uint4*)(O + qkbase + (size_t)(q0 + orow) * 1024 + cb / 2) = ov;
    }
}

// ---------------------------------------------------------------------------
// LayerNorm, bf16 in/out, fp32 stats. One block (256) per row of 1024.
// ---------------------------------------------------------------------------
__global__ __launch_bounds__(256) void ln_bf16_kernel(
        const u16* __restrict__ X, const float* __restrict__ g,
        const float* __restrict__ bta, u16* __restrict__ Y)
{
    __shared__ float red[4];
    const int row = blockIdx.x, tid = threadIdx.x;
    const int wave = tid >> 6, lane = tid & 63;

    const uint2 u = *(const uint2*)(X + (size_t)row * 1024 + tid * 4);
    const float x0 = bflo(u.x), x1 = bfhi(u.x), x2 = bflo(u.y), x3 = bfhi(u.y);

    float s = x0 + x1 + x2 + x3;
    #pragma unroll
    for (int off = 32; off; off >>= 1) s += __shfl_xor(s, off);
    if (lane == 0) red[wave] = s;
    __syncthreads();
    const float mu = (red[0] + red[1] + red[2] + red[3]) * (1.f / 1024.f);
    __syncthreads();

    const float d0 = x0 - mu, d1 = x1 - mu, d2 = x2 - mu, d3 = x3 - mu;
    float s2 = d0 * d0 + d1 * d1 + d2 * d2 + d3 * d3;
    #pragma unroll
    for (int off = 32; off; off >>= 1) s2 += __shfl_xor(s2, off);
    if (lane == 0) red[wave] = s2;
    __syncthreads();
    const float var = (red[0] + red[1] + red[2] + red[3]) * (1.f / 1024.f);
    const float rs = rsqrtf(var + 1e-5f);

    const float4 gg = ((const float4*)g)[tid];
    const float4 bb = ((const float4*)bta)[tid];
    ushort4 o;
    o.x = f2bf(d0 * rs * gg.x + bb.x);
    o.y = f2bf(d1 * rs * gg.y + bb.y);
    o.z = f2bf(d2 * rs * gg.z + bb.z);
    o.w = f2bf(d3 * rs * gg.w + bb.w);
    *(ushort4*)(Y + (size_t)row * 1024 + tid * 4) = o;
}

// final LayerNorm: X0 + X1 (f32 split-K partials) + bf16 residual -> f32 out
__global__ __launch_bounds__(256) void ln_res_kernel(
        const float* X0, const float* __restrict__ X1,
        const u16* __restrict__ res, const float* __restrict__ g,
        const float* __restrict__ bta, float* Y)
{
    __shared__ float red[4];
    const int row = blockIdx.x;
    const int tid = threadIdx.x;
    const int wave = tid >> 6, lane = tid & 63;

    const float4 v0 = ((const float4*)(X0 + (size_t)row * 1024))[tid];
    const float4 v1 = ((const float4*)(X1 + (size_t)row * 1024))[tid];
    const uint2 u = *(const uint2*)(res + (size_t)row * 1024 + tid * 4);
    const float x0 = v0.x + v1.x + bflo(u.x), x1 = v0.y + v1.y + bfhi(u.x);
    const float x2 = v0.z + v1.z + bflo(u.y), x3 = v0.w + v1.w + bfhi(u.y);

    float s = x0 + x1 + x2 + x3;
    #pragma unroll
    for (int off = 32; off; off >>= 1) s += __shfl_xor(s, off);
    if (lane == 0) red[wave] = s;
    __syncthreads();
    const float mu = (red[0] + red[1] + red[2] + red[3]) * (1.f / 1024.f);
    __syncthreads();

    const float d0 = x0 - mu, d1 = x1 - mu, d2 = x2 - mu, d3 = x3 - mu;
    float s2 = d0 * d0 + d1 * d1 + d2 * d2 + d3 * d3;
    #pragma unroll
    for (int off = 32; off; off >>= 1) s2 += __shfl_xor(s2, off);
    if (lane == 0) red[wave] = s2;
    __syncthreads();
    const float var = (red[0] + red[1] + red[2] + red[3]) * (1.f / 1024.f);
    const float rs = rsqrtf(var + 1e-5f);

    const float4 gg = ((const float4*)g)[tid];
    const float4 bb = ((const float4*)bta)[tid];
    float4 o;
    o.x = d0 * rs * gg.x + bb.x;
    o.y = d1 * rs * gg.y + bb.y;
    o.z = d2 * rs * gg.z + bb.z;
    o.w = d3 * rs * gg.w + bb.w;
    ((float4*)(Y + (size_t)row * 1024))[tid] = o;
}

// ---------------------------------------------------------------------------
extern "C" void kernel_launch(void* const* d_in, const int* in_sizes, int n_in,
                              void* d_out, int out_size, void* d_ws, size_t ws_size,
                              hipStream_t stream)
{
    const float* tgt    = (const float*)d_in[0];
    const float* mem    = (const float*)d_in[1];
    const float* sa_wq  = (const float*)d_in[3];
    const float* sa_bq  = (const float*)d_in[4];
    const float* sa_wk  = (const float*)d_in[5];
    const float* sa_bk  = (const float*)d_in[6];
    const float* sa_wv  = (const float*)d_in[7];
    const float* sa_bv  = (const float*)d_in[8];
    const float* sa_wo  = (const float*)d_in[9];
    const float* sa_bo  = (const float*)d_in[10];
    const float* ca_wq  = (const float*)d_in[11];
    const float* ca_bq  = (const float*)d_in[12];
    const float* ca_wk  = (const float*)d_in[13];
    const float* ca_bk  = (const float*)d_in[14];
    const float* ca_wv  = (const float*)d_in[15];
    const float* ca_bv  = (const float*)d_in[16];
    const float* ca_wo  = (const float*)d_in[17];
    const float* ca_bo  = (const float*)d_in[18];
    const float* ffn_w1 = (const float*)d_in[19];
    const float* ffn_b1 = (const float*)d_in[20];
    const float* ffn_w2 = (const float*)d_in[21];
    const float* ffn_b2 = (const float*)d_in[22];
    const float* ln1_g  = (const float*)d_in[23];
    const float* ln1_b  = (const float*)d_in[24];
    const float* ln2_g  = (const float*)d_in[25];
    const float* ln2_b  = (const float*)d_in[26];
    const float* ln3_g  = (const float*)d_in[27];
    const float* ln3_b  = (const float*)d_in[28];

    float* out = (float*)d_out;
    u16* wsb = (u16*)d_ws;
    const size_t M1 = 1024 * 1024;

    u16* Wsq = wsb + 0 * M1;
    u16* Wsk = wsb + 1 * M1;
    u16* Wsv = wsb + 2 * M1;
    u16* Wso = wsb + 3 * M1;
    u16* Wcq = wsb + 4 * M1;
    u16* Wck = wsb + 5 * M1;
    u16* Wcv = wsb + 6 * M1;
    u16* Wco = wsb + 7 * M1;
    u16* Wf1 = wsb + 8 * M1;
    u16* Wf2 = wsb + 12 * M1;

    u16* sl = wsb + 16 * M1;
    u16* s0 = sl + 0 * 4 * M1;
    u16* s1 = sl + 4 * M1;
    u16* s2 = sl + 8 * M1;
    u16* s3 = sl + 12 * M1;
    u16* s4 = sl + 16 * M1;
    u16* s5 = sl + 20 * M1;
    u16* H  = s0;

    float* part1 = (float*)wsb;

    float* biasQKV = (float*)(wsb + 40 * M1);   // [3072]
    float* biasCA  = biasQKV + 3072;            // [3072]

    const dim3 blk(256);
    const dim3 gqkv(24, 32);    // N=3072 fused QKV / fused CA (128x128)
    const dim3 g1(16, 32);      // N=1024 GEMM (128x64)
    const dim3 g4(32, 16);      // N=4096 FFN1 (256x128, MW=8)
    const dim3 gf2(8, 32, 2);   // FFN2 split-K=2 (128x128)
    const dim3 ga(64, 16);      // attention
    const dim3 gln(4096);

    PrepArgs pa;
    pa.w[0] = sa_wq; pa.o[0] = Wsq;
    pa.w[1] = sa_wk; pa.o[1] = Wsk;
    pa.w[2] = sa_wv; pa.o[2] = Wsv;
    pa.w[3] = sa_wo; pa.o[3] = Wso;
    pa.w[4] = ca_wq; pa.o[4] = Wcq;
    pa.w[5] = ca_wk; pa.o[5] = Wck;
    pa.w[6] = ca_wv; pa.o[6] = Wcv;
    pa.w[7] = ca_wo; pa.o[7] = Wco;
    pa.w[8] = ffn_w1; pa.o[8] = Wf1;
    pa.w[9] = ffn_w2; pa.o[9] = Wf2;
    pa.tgt = tgt; pa.mem = mem; pa.tgtb = s0; pa.memb = s1;
    pa.bq = sa_bq; pa.bk = sa_bk; pa.bv = sa_bv;
    pa.cbq = ca_bq; pa.cbk = ca_bk; pa.cbv = ca_bv;
    pa.biasQKV = biasQKV; pa.biasCA = biasCA;
    prep_kernel<<<12308, blk, 0, stream>>>(pa);

    // ---- self-attention ----
    // fused QKV: Q(pre-scaled)->s2, K->s3, Vt->s4
    gemm_mfma<5, 4, 4><<<gqkv, blk, 0, stream>>>(s0, Wsq, biasQKV, nullptr,
                                                 s2, s3, s4, nullptr, 3072, 1024);
    fattn_mfma<1><<<ga, blk, 0, stream>>>(s2, s3, s4, s5);
    gemm_mfma<2, 2, 4><<<g1, blk, 0, stream>>>(s5, Wso, sa_bo, s0, s2, nullptr, nullptr, nullptr, 1024, 1024);
    ln_bf16_kernel<<<gln, blk, 0, stream>>>(s2, ln1_g, ln1_b, s3);     // x1 = s3

    // ---- cross-attention ----
    // fused CA projections (EPI 9): seg0 Q from x1 (s3), seg1/2 K,Vt from mem (s1)
    // Q->s2, K->s4, Vt->s5 (Wcq/Wck/Wcv contiguous => one Bt)
    gemm_mfma<9, 4, 4><<<gqkv, blk, 0, stream>>>(s3, Wcq, biasCA, nullptr,
                                                 s2, s4, s5, s1, 3072, 1024);
    fattn_mfma<0><<<ga, blk, 0, stream>>>(s2, s4, s5, s0);
    gemm_mfma<2, 2, 4><<<g1, blk, 0, stream>>>(s0, Wco, ca_bo, s3, s2, nullptr, nullptr, nullptr, 1024, 1024);
    ln_bf16_kernel<<<gln, blk, 0, stream>>>(s2, ln2_g, ln2_b, s4);     // x2 = s4

    // ---- FFN ----
    gemm_mfma<1, 4, 8><<<g4, blk, 0, stream>>>(s4, Wf1, ffn_b1, nullptr, H, nullptr, nullptr, nullptr, 4096, 1024);
    gemm_mfma<7, 4, 4><<<gf2, blk, 0, stream>>>(H, Wf2, ffn_b2, nullptr, out,
                                                (u16*)part1, nullptr, nullptr, 1024, 4096);
    ln_res_kernel<<<gln, blk, 0, stream>>>(out, part1, s4, ln3_g, ln3_b, out);
}

// Round 21
// 305.276 us; speedup vs baseline: 1.1016x; 1.0175x over previous
//
#include <hip/hip_runtime.h>
#include <hip/hip_bf16.h>

typedef unsigned short u16;
typedef __attribute__((ext_vector_type(8))) short bf16x8;
typedef __attribute__((ext_vector_type(4))) float floatx4;

__device__ inline float u2f(unsigned u) { union { unsigned i; float f; } x; x.i = u; return x.f; }
__device__ inline float bflo(unsigned p) { return u2f(p << 16); }
__device__ inline float bfhi(unsigned p) { return u2f(p & 0xffff0000u); }
__device__ inline u16 f2bf(float f) {
    union { __hip_bfloat16 h; u16 u; } x;
    x.h = __float2bfloat16(f);
    return x.u;
}
__device__ inline unsigned pk2bf(float lo, float hi) {
    return ((unsigned)f2bf(hi) << 16) | f2bf(lo);
}

#define SCLQ 0.18033688011f   // 0.125 * log2(e), folded into Q

#define GLDS(g, l) __builtin_amdgcn_global_load_lds( \
    (const __attribute__((address_space(1))) void*)(g), \
    (__attribute__((address_space(3))) void*)(l), 16, 0, 0)

// ---------------------------------------------------------------------------
// bf16 MFMA GEMM: C[M,N] = A[M,K] @ Bt[N,K]^T + bias (+res) (+relu)
// Block tile (MW*32) x (NF*32), 4 waves (2x2), 16x16x32 MFMA, BK=32,
// XCD-chunked swizzle, 3-buffer counted-vmcnt pipeline (stage t+2, steady
// wait vmcnt(LOADS), drain only on last tile).
//   MW=4: 128-row block;  MW=8: 256-row block (FFN1, better MFMA:ds ratio).
// EPI: 0 bf16, 1 +relu, 2 +bf16 res,
//      5 seg QKV (seg0 Q*SCLQ -> Cv, seg1 K -> o1, seg2 Vt -> o2),
//      6 seg KV (seg0 K -> Cv, seg1 Vt -> o1),
//      7 split-K f32 partials (z0 -> Cv +bias, z1 -> o1), 8 bf16 * SCLQ,
//      9 = EPI 5 with per-segment A: seg0 reads A (x1), seg1/2 read A2 (mem).
// Vt layout: Vt[b*16+h][d][t], t fast.
// ---------------------------------------------------------------------------
template<int EPI, int NF, int MW>
__global__ __launch_bounds__(256, (MW == 8) ? 2 : 3) void gemm_mfma(
        const u16* __restrict__ A, const u16* __restrict__ Bt,
        const float* __restrict__ bias, const u16* __restrict__ res,
        void* __restrict__ Cv, u16* __restrict__ o1, u16* __restrict__ o2,
        const u16* __restrict__ A2, int N, int K)
{
    constexpr int BN = NF * 32;
    constexpr int BM = MW * 32;
    constexpr int MFR = BM / 32;
    constexpr int ALOADS = BM / 64;
    constexpr int BLOADS = BN / 64;
    constexpr int LOADS = ALOADS + BLOADS;

    __shared__ u16 As0[BM * 32];
    __shared__ u16 Bs0[BN * 32];
    __shared__ u16 As1[BM * 32];
    __shared__ u16 Bs1[BN * 32];
    __shared__ u16 As2[BM * 32];
    __shared__ u16 Bs2[BN * 32];

    const int tid = threadIdx.x;
    const int lane = tid & 63, wv = tid >> 6;
    const int wr = wv >> 1, wc = wv & 1;

    const int gx = gridDim.x;
    const int nwg = gx * gridDim.y;
    const int bid0 = blockIdx.y * gx + blockIdx.x;
    const int nbid = (bid0 & 7) * (nwg >> 3) + (bid0 >> 3);
    const int bx = nbid % gx, by = nbid / gx;
    const int row0 = by * BM, col0 = bx * BN;

    const int Keff = (EPI == 7) ? (K >> 1) : K;
    const int k0off = (EPI == 7) ? blockIdx.z * Keff : 0;

    // EPI 9: per-segment A source (block-uniform; 1024 % BN == 0)
    const u16* Abase = (EPI == 9 && col0 >= 1024) ? A2 : A;

    const u16* pa[ALOADS];
    int ldst[ALOADS];
    #pragma unroll
    for (int i = 0; i < ALOADS; ++i) {
        const int idx = i * 256 + tid;
        const int r = idx >> 2;
        const int kob = (idx & 3) << 4;
        const int sw = kob ^ (((r >> 1) & 3) << 4);
        pa[i] = Abase + (size_t)(row0 + r) * K + k0off + (sw >> 1);
        ldst[i] = idx * 8;
    }
    const u16* pb[BLOADS];
    int ldstB[BLOADS];
    #pragma unroll
    for (int i = 0; i < BLOADS; ++i) {
        const int idx = i * 256 + tid;
        const int r = idx >> 2;
        const int kob = (idx & 3) << 4;
        const int sw = kob ^ (((r >> 1) & 3) << 4);
        pb[i] = Bt + (size_t)(col0 + r) * K + k0off + (sw >> 1);
        ldstB[i] = idx * 8;
    }

    int offa[MFR], offb[NF];
    const int rsel = lane & 15, slot = lane >> 4;
    #pragma unroll
    for (int m = 0; m < MFR; ++m) {
        const int ra = wr * (BM / 2) + m * 16 + rsel;
        offa[m] = ra * 32 + (((slot << 4) ^ (((ra >> 1) & 3) << 4)) >> 1);
    }
    #pragma unroll
    for (int n = 0; n < NF; ++n) {
        const int rb = wc * (NF * 16) + n * 16 + rsel;
        offb[n] = rb * 32 + (((slot << 4) ^ (((rb >> 1) & 3) << 4)) >> 1);
    }

    floatx4 acc[MFR][NF] = {};

#define STAGE(AA, BB, t) do {                                   \
        const int ko_ = (t) << 5;                               \
        _Pragma("unroll")                                       \
        for (int i = 0; i < ALOADS; ++i)                        \
            GLDS(pa[i] + ko_, &AA[ldst[i]]);                    \
        _Pragma("unroll")                                       \
        for (int i = 0; i < BLOADS; ++i)                        \
            GLDS(pb[i] + ko_, &BB[ldstB[i]]);                   \
    } while (0)

#define COMPUTE(AA, BB) do {                                    \
        bf16x8 af[MFR], bfr[NF];                                \
        _Pragma("unroll")                                       \
        for (int m = 0; m < MFR; ++m) af[m] = *(const bf16x8*)&AA[offa[m]]; \
        _Pragma("unroll")                                       \
        for (int n = 0; n < NF; ++n) bfr[n] = *(const bf16x8*)&BB[offb[n]]; \
        _Pragma("unroll")                                       \
        for (int m = 0; m < MFR; ++m)                           \
            _Pragma("unroll")                                   \
            for (int n = 0; n < NF; ++n)                        \
                acc[m][n] = __builtin_amdgcn_mfma_f32_16x16x32_bf16( \
                        af[m], bfr[n], acc[m][n], 0, 0, 0);     \
    } while (0)

#define PHASE(CA, CB, NA, NB, t) do {                           \
        if ((t) < nkt - 1) {                                    \
            if constexpr (LOADS == 6)                           \
                asm volatile("s_waitcnt vmcnt(6)" ::: "memory");\
            else if constexpr (LOADS == 4)                      \
                asm volatile("s_waitcnt vmcnt(4)" ::: "memory");\
            else                                                \
                asm volatile("s_waitcnt vmcnt(3)" ::: "memory");\
        } else {                                                \
            asm volatile("s_waitcnt vmcnt(0)" ::: "memory");    \
        }                                                       \
        __builtin_amdgcn_s_barrier();                           \
        __builtin_amdgcn_sched_barrier(0);                      \
        if ((t) + 2 < nkt) STAGE(NA, NB, (t) + 2);              \
        COMPUTE(CA, CB);                                        \
    } while (0)

    const int nkt = Keff >> 5;       // 32, 64, 128
    STAGE(As0, Bs0, 0);
    STAGE(As1, Bs1, 1);
    int t = 0;
    for (; t + 3 <= nkt; t += 3) {
        PHASE(As0, Bs0, As2, Bs2, t);
        PHASE(As1, Bs1, As0, Bs0, t + 1);
        PHASE(As2, Bs2, As1, Bs1, t + 2);
    }
    if (t < nkt)     PHASE(As0, Bs0, As2, Bs2, t);
    if (t + 1 < nkt) PHASE(As1, Bs1, As0, Bs0, t + 1);
#undef STAGE
#undef COMPUTE
#undef PHASE

    const int cr4 = (lane >> 4) * 4;
    const int cc = lane & 15;

    if (EPI == 7) {
        float* dst = (blockIdx.z == 0) ? (float*)Cv : (float*)o1;
        const bool addb = (blockIdx.z == 0);
        #pragma unroll
        for (int n = 0; n < NF; ++n) {
            const int col = col0 + wc * (NF * 16) + n * 16 + cc;
            const float bv = addb ? bias[col] : 0.f;
            #pragma unroll
            for (int m = 0; m < MFR; ++m) {
                const int rowb = row0 + wr * (BM / 2) + m * 16 + cr4;
                #pragma unroll
                for (int r = 0; r < 4; ++r)
                    dst[(size_t)(rowb + r) * N + col] = acc[m][n][r] + bv;
            }
        }
        return;
    }

    if (EPI == 5 || EPI == 6 || EPI == 9) {
        const int seg = col0 >> 10;
        const int vtseg = (EPI == 6) ? 1 : 2;
        u16* dst;
        if (EPI == 6) dst = (seg == 0) ? (u16*)Cv : o1;
        else          dst = (seg == 0) ? (u16*)Cv : (seg == 1 ? o1 : o2);

        if (seg == vtseg) {
            #pragma unroll
            for (int n = 0; n < NF; ++n) {
                const int col = col0 + wc * (NF * 16) + n * 16 + cc;
                const float bv = bias[col];
                const int vcol = col & 1023;
                const int h = vcol >> 6, d = vcol & 63;
                #pragma unroll
                for (int m = 0; m < MFR; ++m) {
                    const int tk = row0 + wr * (BM / 2) + m * 16 + cr4;
                    const int b = tk >> 10;
                    ushort4 o4;
                    o4.x = f2bf(acc[m][n][0] + bv);
                    o4.y = f2bf(acc[m][n][1] + bv);
                    o4.z = f2bf(acc[m][n][2] + bv);
                    o4.w = f2bf(acc[m][n][3] + bv);
                    *(ushort4*)(dst +
                        (((size_t)(b * 16 + h) * 64 + d) * 1024 + (tk & 1023))) = o4;
                }
            }
        } else {
            const float osc = ((EPI == 5 || EPI == 9) && seg == 0) ? SCLQ : 1.f;
            #pragma unroll
            for (int n = 0; n < NF; ++n) {
                const int col = col0 + wc * (NF * 16) + n * 16 + cc;
                const float bv = bias[col];
                const int oc = col & 1023;
                #pragma unroll
                for (int m = 0; m < MFR; ++m) {
                    const int rowb = row0 + wr * (BM / 2) + m * 16 + cr4;
                    #pragma unroll
                    for (int r = 0; r < 4; ++r)
                        dst[(size_t)(rowb + r) * 1024 + oc] = f2bf((acc[m][n][r] + bv) * osc);
                }
            }
        }
        return;
    }

    #pragma unroll
    for (int n = 0; n < NF; ++n) {
        const int col = col0 + wc * (NF * 16) + n * 16 + cc;
        const float bv = bias[col];
        #pragma unroll
        for (int m = 0; m < MFR; ++m) {
            const int rowb = row0 + wr * (BM / 2) + m * 16 + cr4;
            #pragma unroll
            for (int r = 0; r < 4; ++r) {
                float v = acc[m][n][r] + bv;
                const size_t o = (size_t)(rowb + r) * N + col;
                if (EPI == 2) v += u2f((unsigned)res[o] << 16);
                if (EPI == 1) v = fmaxf(v, 0.f);
                if (EPI == 8) v *= SCLQ;
                ((u16*)Cv)[o] = f2bf(v);
            }
        }
    }
}

// ---------------------------------------------------------------------------
// Fused prep: 10 weight transposes (f32->bf16, W[K,N] -> Wt[N,K]) +
// tgt/mem f32->bf16 conversion + bias concat, all in ONE dispatch.
// ---------------------------------------------------------------------------
struct PrepArgs {
    const float* w[10];
    u16* o[10];
    const float* tgt; const float* mem;
    u16* tgtb; u16* memb;
    const float* bq; const float* bk; const float* bv;      // sa biases
    const float* cbq; const float* cbk; const float* cbv;   // ca biases
    float* biasQKV; float* biasCA;
};

__global__ __launch_bounds__(256) void prep_kernel(PrepArgs p)
{
    __shared__ float ts[64][65];
    const int tid = threadIdx.x;
    int bid = blockIdx.x;

    if (bid < 4096) {
        int w, n0, k0, K, N;
        if (bid < 2048) {
            w = bid >> 8;
            const int t = bid & 255;
            n0 = (t & 15) * 64; k0 = ((t >> 4) & 15) * 64; K = 1024; N = 1024;
        } else if (bid < 3072) {
            w = 8;
            const int t = bid - 2048;
            n0 = (t & 63) * 64; k0 = (t >> 6) * 64; K = 1024; N = 4096;
        } else {
            w = 9;
            const int t = bid - 3072;
            n0 = (t & 15) * 64; k0 = (t >> 4) * 64; K = 4096; N = 1024;
        }
        const float* __restrict__ W = p.w[w];
        u16* __restrict__ Wt = p.o[w];
        const int tr = tid >> 4, tc4 = (tid & 15) * 4;
        #pragma unroll
        for (int i = 0; i < 4; ++i) {
            const float4 v = *(const float4*)(W + (size_t)(k0 + tr + i * 16) * N + n0 + tc4);
            ts[tr + i * 16][tc4 + 0] = v.x;
            ts[tr + i * 16][tc4 + 1] = v.y;
            ts[tr + i * 16][tc4 + 2] = v.z;
            ts[tr + i * 16][tc4 + 3] = v.w;
        }
        __syncthreads();
        #pragma unroll
        for (int i = 0; i < 4; ++i) {
            const int nr = tr + i * 16;
            ushort4 o;
            o.x = f2bf(ts[tc4 + 0][nr]);
            o.y = f2bf(ts[tc4 + 1][nr]);
            o.z = f2bf(ts[tc4 + 2][nr]);
            o.w = f2bf(ts[tc4 + 3][nr]);
            *(ushort4*)(Wt + (size_t)(n0 + nr) * K + k0 + tc4) = o;
        }
        return;
    }
    bid -= 4096;
    if (bid < 4096) {
        const int i = bid * 256 + tid;
        const float4 v = ((const float4*)p.tgt)[i];
        ushort4 o;
        o.x = f2bf(v.x); o.y = f2bf(v.y); o.z = f2bf(v.z); o.w = f2bf(v.w);
        ((ushort4*)p.tgtb)[i] = o;
        return;
    }
    bid -= 4096;
    if (bid < 4096) {
        const int i = bid * 256 + tid;
        const float4 v = ((const float4*)p.mem)[i];
        ushort4 o;
        o.x = f2bf(v.x); o.y = f2bf(v.y); o.z = f2bf(v.z); o.w = f2bf(v.w);
        ((ushort4*)p.memb)[i] = o;
        return;
    }
    bid -= 4096;
    const int i = bid * 256 + tid;
    if (i < 3072) {
        p.biasQKV[i] = (i < 1024) ? p.bq[i] : (i < 2048 ? p.bk[i - 1024] : p.bv[i - 2048]);
        p.biasCA[i]  = (i < 1024) ? p.cbq[i] : (i < 2048 ? p.cbk[i - 1024] : p.cbv[i - 2048]);
    }
}

// ---------------------------------------------------------------------------
// MFMA flash attention, swapped-operand, STATIC-MAX softmax.
// Q pre-scaled by 0.125*log2(e) upstream; P = exp2(s) directly.
// s_setprio(1) around MFMA clusters (T5): with up to 6 co-resident blocks/CU
// the scheduler favors MFMA-entering waves over other blocks' staging waves.
// Grid (64, 16). LDS 24 KB.
// ---------------------------------------------------------------------------
template<int CAUSAL>
__global__ __launch_bounds__(256) void fattn_mfma(
        const u16* __restrict__ Q, const u16* __restrict__ K,
        const u16* __restrict__ Vt, u16* __restrict__ O)
{
    __shared__ u16 Ks[64 * 64];
    __shared__ u16 Vs[64 * 64];
    __shared__ u16 Ps[64 * 64];

    const int tid = threadIdx.x;
    const int lane = tid & 63, wv = tid >> 6;
    const int g = lane >> 4, qx = lane & 15;
    const int bh = blockIdx.x;
    const int b = bh >> 4, h = bh & 15;
    const int qt = blockIdx.y, q0 = qt * 64;

    const size_t qkbase = (size_t)b * (1024 * 1024) + (size_t)h * 64;
    const size_t vtbase = (size_t)bh * 64 * 1024;

    const int qr = wv * 16 + qx;
    const int qg = q0 + qr;
    const int swzq = (qr & 7) << 4;

    bf16x8 qf[2];
    #pragma unroll
    for (int ks = 0; ks < 2; ++ks)
        qf[ks] = *(const bf16x8*)(Q + qkbase + (size_t)qg * 1024 + ks * 32 + g * 8);

    const int r0 = tid >> 3, s0 = tid & 7;

    float l_i = 0.f;
    floatx4 o_acc[4] = {};

    const int ktmax = CAUSAL ? qt : 15;
    for (int kt = 0; kt <= ktmax; ++kt) {
        __syncthreads();
        #pragma unroll
        for (int i = 0; i < 2; ++i) {
            const int r = i * 32 + r0;
            const uint4 kv = *(const uint4*)(K + qkbase + (size_t)(kt * 64 + r) * 1024 + s0 * 8);
            *(uint4*)((char*)Ks + r * 128 + ((s0 ^ (r & 7)) << 4)) = kv;
            const uint4 vv = *(const uint4*)(Vt + vtbase + (size_t)r * 1024 + kt * 64 + s0 * 8);
            *(uint4*)((char*)Vs + r * 128 + ((s0 ^ (r & 7)) << 4)) = vv;
        }
        __syncthreads();

        __builtin_amdgcn_s_setprio(1);
        floatx4 sa[4] = {};
        #pragma unroll
        for (int ks = 0; ks < 2; ++ks) {
            #pragma unroll
            for (int m = 0; m < 4; ++m) {
                const int rr = m * 16 + qx;
                const int sl = ks * 4 + g;
                const bf16x8 kf = *(const bf16x8*)((char*)Ks + rr * 128 + ((sl ^ (rr & 7)) << 4));
                sa[m] = __builtin_amdgcn_mfma_f32_16x16x32_bf16(kf, qf[ks], sa[m], 0, 0, 0);
            }
        }
        __builtin_amdgcn_s_setprio(0);

        float p[4][4];
        float rs = 0.f;
        #pragma unroll
        for (int m = 0; m < 4; ++m)
            #pragma unroll
            for (int r = 0; r < 4; ++r) {
                float e = exp2f(sa[m][r]);
                if (CAUSAL && kt == qt) {
                    const int kl = m * 16 + g * 4 + r;
                    if (kl > qr) e = 0.f;
                }
                p[m][r] = e;
                rs += e;
            }
        rs += __shfl_xor(rs, 16);
        rs += __shfl_xor(rs, 32);
        l_i += rs;

        #pragma unroll
        for (int m = 0; m < 4; ++m) {
            uint2 pk;
            pk.x = pk2bf(p[m][0], p[m][1]);
            pk.y = pk2bf(p[m][2], p[m][3]);
            *(uint2*)((char*)Ps + qr * 128 + ((m * 32 + g * 8) ^ swzq)) = pk;
        }

        __builtin_amdgcn_s_setprio(1);
        #pragma unroll
        for (int ks2 = 0; ks2 < 2; ++ks2) {
            const bf16x8 pf = *(const bf16x8*)((char*)Ps + qr * 128 + ((ks2 * 64 + g * 16) ^ swzq));
            #pragma unroll
            for (int n = 0; n < 4; ++n) {
                const int rv = n * 16 + qx;
                const int sl = ks2 * 4 + g;
                const bf16x8 vf = *(const bf16x8*)((char*)Vs + rv * 128 + ((sl ^ (rv & 7)) << 4));
                o_acc[n] = __builtin_amdgcn_mfma_f32_16x16x32_bf16(vf, pf, o_acc[n], 0, 0, 0);
            }
        }
        __builtin_amdgcn_s_setprio(0);
    }

    const float inv = 1.f / l_i;
    #pragma unroll
    for (int n = 0; n < 4; ++n) {
        uint2 ov;
        ov.x = pk2bf(o_acc[n][0] * inv, o_acc[n][1] * inv);
        ov.y = pk2bf(o_acc[n][2] * inv, o_acc[n][3] * inv);
        *(uint2*)((char*)Ps + qr * 128 + ((n * 32 + g * 8) ^ swzq)) = ov;
    }
    const int orow = wv * 16 + (lane >> 2);
    const int swzo = (orow & 7) << 4;
    #pragma unroll
    for (int i = 0; i < 2; ++i) {
        const int cb = ((lane & 3) * 2 + i) * 16;
        const uint4 ov = *(const uint4*)((char*)Ps + orow * 128 + (cb ^ swzo));
        *(uint4*)(O + qkbase + (size_t)(q0 + orow) * 1024 + cb / 2) = ov;
    }
}

// ---------------------------------------------------------------------------
// LayerNorm, bf16 in/out, fp32 stats. One block (256) per row of 1024.
// ---------------------------------------------------------------------------
__global__ __launch_bounds__(256) void ln_bf16_kernel(
        const u16* __restrict__ X, const float* __restrict__ g,
        const float* __restrict__ bta, u16* __restrict__ Y)
{
    __shared__ float red[4];
    const int row = blockIdx.x, tid = threadIdx.x;
    const int wave = tid >> 6, lane = tid & 63;

    const uint2 u = *(const uint2*)(X + (size_t)row * 1024 + tid * 4);
    const float x0 = bflo(u.x), x1 = bfhi(u.x), x2 = bflo(u.y), x3 = bfhi(u.y);

    float s = x0 + x1 + x2 + x3;
    #pragma unroll
    for (int off = 32; off; off >>= 1) s += __shfl_xor(s, off);
    if (lane == 0) red[wave] = s;
    __syncthreads();
    const float mu = (red[0] + red[1] + red[2] + red[3]) * (1.f / 1024.f);
    __syncthreads();

    const float d0 = x0 - mu, d1 = x1 - mu, d2 = x2 - mu, d3 = x3 - mu;
    float s2 = d0 * d0 + d1 * d1 + d2 * d2 + d3 * d3;
    #pragma unroll
    for (int off = 32; off; off >>= 1) s2 += __shfl_xor(s2, off);
    if (lane == 0) red[wave] = s2;
    __syncthreads();
    const float var = (red[0] + red[1] + red[2] + red[3]) * (1.f / 1024.f);
    const float rs = rsqrtf(var + 1e-5f);

    const float4 gg = ((const float4*)g)[tid];
    const float4 bb = ((const float4*)bta)[tid];
    ushort4 o;
    o.x = f2bf(d0 * rs * gg.x + bb.x);
    o.y = f2bf(d1 * rs * gg.y + bb.y);
    o.z = f2bf(d2 * rs * gg.z + bb.z);
    o.w = f2bf(d3 * rs * gg.w + bb.w);
    *(ushort4*)(Y + (size_t)row * 1024 + tid * 4) = o;
}

// final LayerNorm: X0 + X1 (f32 split-K partials) + bf16 residual -> f32 out
__global__ __launch_bounds__(256) void ln_res_kernel(
        const float* X0, const float* __restrict__ X1,
        const u16* __restrict__ res, const float* __restrict__ g,
        const float* __restrict__ bta, float* Y)
{
    __shared__ float red[4];
    const int row = blockIdx.x;
    const int tid = threadIdx.x;
    const int wave = tid >> 6, lane = tid & 63;

    const float4 v0 = ((const float4*)(X0 + (size_t)row * 1024))[tid];
    const float4 v1 = ((const float4*)(X1 + (size_t)row * 1024))[tid];
    const uint2 u = *(const uint2*)(res + (size_t)row * 1024 + tid * 4);
    const float x0 = v0.x + v1.x + bflo(u.x), x1 = v0.y + v1.y + bfhi(u.x);
    const float x2 = v0.z + v1.z + bflo(u.y), x3 = v0.w + v1.w + bfhi(u.y);

    float s = x0 + x1 + x2 + x3;
    #pragma unroll
    for (int off = 32; off; off >>= 1) s += __shfl_xor(s, off);
    if (lane == 0) red[wave] = s;
    __syncthreads();
    const float mu = (red[0] + red[1] + red[2] + red[3]) * (1.f / 1024.f);
    __syncthreads();

    const float d0 = x0 - mu, d1 = x1 - mu, d2 = x2 - mu, d3 = x3 - mu;
    float s2 = d0 * d0 + d1 * d1 + d2 * d2 + d3 * d3;
    #pragma unroll
    for (int off = 32; off; off >>= 1) s2 += __shfl_xor(s2, off);
    if (lane == 0) red[wave] = s2;
    __syncthreads();
    const float var = (red[0] + red[1] + red[2] + red[3]) * (1.f / 1024.f);
    const float rs = rsqrtf(var + 1e-5f);

    const float4 gg = ((const float4*)g)[tid];
    const float4 bb = ((const float4*)bta)[tid];
    float4 o;
    o.x = d0 * rs * gg.x + bb.x;
    o.y = d1 * rs * gg.y + bb.y;
    o.z = d2 * rs * gg.z + bb.z;
    o.w = d3 * rs * gg.w + bb.w;
    ((float4*)(Y + (size_t)row * 1024))[tid] = o;
}

// ---------------------------------------------------------------------------
extern "C" void kernel_launch(void* const* d_in, const int* in_sizes, int n_in,
                              void* d_out, int out_size, void* d_ws, size_t ws_size,
                              hipStream_t stream)
{
    const float* tgt    = (const float*)d_in[0];
    const float* mem    = (const float*)d_in[1];
    const float* sa_wq  = (const float*)d_in[3];
    const float* sa_bq  = (const float*)d_in[4];
    const float* sa_wk  = (const float*)d_in[5];
    const float* sa_bk  = (const float*)d_in[6];
    const float* sa_wv  = (const float*)d_in[7];
    const float* sa_bv  = (const float*)d_in[8];
    const float* sa_wo  = (const float*)d_in[9];
    const float* sa_bo  = (const float*)d_in[10];
    const float* ca_wq  = (const float*)d_in[11];
    const float* ca_bq  = (const float*)d_in[12];
    const float* ca_wk  = (const float*)d_in[13];
    const float* ca_bk  = (const float*)d_in[14];
    const float* ca_wv  = (const float*)d_in[15];
    const float* ca_bv  = (const float*)d_in[16];
    const float* ca_wo  = (const float*)d_in[17];
    const float* ca_bo  = (const float*)d_in[18];
    const float* ffn_w1 = (const float*)d_in[19];
    const float* ffn_b1 = (const float*)d_in[20];
    const float* ffn_w2 = (const float*)d_in[21];
    const float* ffn_b2 = (const float*)d_in[22];
    const float* ln1_g  = (const float*)d_in[23];
    const float* ln1_b  = (const float*)d_in[24];
    const float* ln2_g  = (const float*)d_in[25];
    const float* ln2_b  = (const float*)d_in[26];
    const float* ln3_g  = (const float*)d_in[27];
    const float* ln3_b  = (const float*)d_in[28];

    float* out = (float*)d_out;
    u16* wsb = (u16*)d_ws;
    const size_t M1 = 1024 * 1024;

    u16* Wsq = wsb + 0 * M1;
    u16* Wsk = wsb + 1 * M1;
    u16* Wsv = wsb + 2 * M1;
    u16* Wso = wsb + 3 * M1;
    u16* Wcq = wsb + 4 * M1;
    u16* Wck = wsb + 5 * M1;
    u16* Wcv = wsb + 6 * M1;
    u16* Wco = wsb + 7 * M1;
    u16* Wf1 = wsb + 8 * M1;
    u16* Wf2 = wsb + 12 * M1;

    u16* sl = wsb + 16 * M1;
    u16* s0 = sl + 0 * 4 * M1;
    u16* s1 = sl + 4 * M1;
    u16* s2 = sl + 8 * M1;
    u16* s3 = sl + 12 * M1;
    u16* s4 = sl + 16 * M1;
    u16* s5 = sl + 20 * M1;
    u16* H  = s0;

    float* part1 = (float*)wsb;

    float* biasQKV = (float*)(wsb + 40 * M1);   // [3072]
    float* biasCA  = biasQKV + 3072;            // [3072]

    const dim3 blk(256);
    const dim3 gqkv(24, 32);    // N=3072 fused QKV / fused CA (128x128)
    const dim3 g1(16, 32);      // N=1024 GEMM (128x64)
    const dim3 g4(32, 16);      // N=4096 FFN1 (256x128, MW=8)
    const dim3 gf2(8, 32, 2);   // FFN2 split-K=2 (128x128)
    const dim3 ga(64, 16);      // attention
    const dim3 gln(4096);

    PrepArgs pa;
    pa.w[0] = sa_wq; pa.o[0] = Wsq;
    pa.w[1] = sa_wk; pa.o[1] = Wsk;
    pa.w[2] = sa_wv; pa.o[2] = Wsv;
    pa.w[3] = sa_wo; pa.o[3] = Wso;
    pa.w[4] = ca_wq; pa.o[4] = Wcq;
    pa.w[5] = ca_wk; pa.o[5] = Wck;
    pa.w[6] = ca_wv; pa.o[6] = Wcv;
    pa.w[7] = ca_wo; pa.o[7] = Wco;
    pa.w[8] = ffn_w1; pa.o[8] = Wf1;
    pa.w[9] = ffn_w2; pa.o[9] = Wf2;
    pa.tgt = tgt; pa.mem = mem; pa.tgtb = s0; pa.memb = s1;
    pa.bq = sa_bq; pa.bk = sa_bk; pa.bv = sa_bv;
    pa.cbq = ca_bq; pa.cbk = ca_bk; pa.cbv = ca_bv;
    pa.biasQKV = biasQKV; pa.biasCA = biasCA;
    prep_kernel<<<12308, blk, 0, stream>>>(pa);

    // ---- self-attention ----
    // fused QKV: Q(pre-scaled)->s2, K->s3, Vt->s4
    gemm_mfma<5, 4, 4><<<gqkv, blk, 0, stream>>>(s0, Wsq, biasQKV, nullptr,
                                                 s2, s3, s4, nullptr, 3072, 1024);
    fattn_mfma<1><<<ga, blk, 0, stream>>>(s2, s3, s4, s5);
    gemm_mfma<2, 2, 4><<<g1, blk, 0, stream>>>(s5, Wso, sa_bo, s0, s2, nullptr, nullptr, nullptr, 1024, 1024);
    ln_bf16_kernel<<<gln, blk, 0, stream>>>(s2, ln1_g, ln1_b, s3);     // x1 = s3

    // ---- cross-attention ----
    // fused CA projections (EPI 9): seg0 Q from x1 (s3), seg1/2 K,Vt from mem (s1)
    gemm_mfma<9, 4, 4><<<gqkv, blk, 0, stream>>>(s3, Wcq, biasCA, nullptr,
                                                 s2, s4, s5, s1, 3072, 1024);
    fattn_mfma<0><<<ga, blk, 0, stream>>>(s2, s4, s5, s0);
    gemm_mfma<2, 2, 4><<<g1, blk, 0, stream>>>(s0, Wco, ca_bo, s3, s2, nullptr, nullptr, nullptr, 1024, 1024);
    ln_bf16_kernel<<<gln, blk, 0, stream>>>(s2, ln2_g, ln2_b, s4);     // x2 = s4

    // ---- FFN ----
    gemm_mfma<1, 4, 8><<<g4, blk, 0, stream>>>(s4, Wf1, ffn_b1, nullptr, H, nullptr, nullptr, nullptr, 4096, 1024);
    gemm_mfma<7, 4, 4><<<gf2, blk, 0, stream>>>(H, Wf2, ffn_b2, nullptr, out,
                                                (u16*)part1, nullptr, nullptr, 1024, 4096);
    ln_res_kernel<<<gln, blk, 0, stream>>>(out, part1, s4, ln3_g, ln3_b, out);
}

// Round 22
// 301.124 us; speedup vs baseline: 1.1167x; 1.0138x over previous
//
#include <hip/hip_runtime.h>
#include <hip/hip_bf16.h>

typedef unsigned short u16;
typedef __attribute__((ext_vector_type(8))) short bf16x8;
typedef __attribute__((ext_vector_type(4))) float floatx4;

__device__ inline float u2f(unsigned u) { union { unsigned i; float f; } x; x.i = u; return x.f; }
__device__ inline float bflo(unsigned p) { return u2f(p << 16); }
__device__ inline float bfhi(unsigned p) { return u2f(p & 0xffff0000u); }
__device__ inline u16 f2bf(float f) {
    union { __hip_bfloat16 h; u16 u; } x;
    x.h = __float2bfloat16(f);
    return x.u;
}
__device__ inline unsigned pk2bf(float lo, float hi) {
    return ((unsigned)f2bf(hi) << 16) | f2bf(lo);
}

#define SCLQ 0.18033688011f   // 0.125 * log2(e), folded into Q

#define GLDS(g, l) __builtin_amdgcn_global_load_lds( \
    (const __attribute__((address_space(1))) void*)(g), \
    (__attribute__((address_space(3))) void*)(l), 16, 0, 0)

// ---------------------------------------------------------------------------
// bf16 MFMA GEMM: C[M,N] = A[M,K] @ Bt[N,K]^T + bias (+res) (+relu)
// Block tile (MW*32) x (NF*32), 4 waves (2x2), 16x16x32 MFMA, BK=32,
// XCD-chunked swizzle, 3-buffer counted-vmcnt pipeline (stage t+2, steady
// wait vmcnt(LOADS), drain only on last tile).
//   MW=4: 128-row block;  MW=8: 256-row block (FFN1, better MFMA:ds ratio).
// EPI: 0 bf16, 1 +relu, 2 +bf16 res,
//      5 seg QKV (seg0 Q*SCLQ -> Cv, seg1 K -> o1, seg2 Vt -> o2),
//      6 seg KV (seg0 K -> Cv, seg1 Vt -> o1),
//      7 split-K f32 partials (z0 -> Cv +bias, z1 -> o1), 8 bf16 * SCLQ,
//      9 = EPI 5 with per-segment A: seg0 reads A (x1), seg1/2 read A2 (mem).
// Vt layout: Vt[b*16+h][d][t], t fast.
// ---------------------------------------------------------------------------
template<int EPI, int NF, int MW>
__global__ __launch_bounds__(256, (MW == 8) ? 2 : 3) void gemm_mfma(
        const u16* __restrict__ A, const u16* __restrict__ Bt,
        const float* __restrict__ bias, const u16* __restrict__ res,
        void* __restrict__ Cv, u16* __restrict__ o1, u16* __restrict__ o2,
        const u16* __restrict__ A2, int N, int K)
{
    constexpr int BN = NF * 32;
    constexpr int BM = MW * 32;
    constexpr int MFR = BM / 32;
    constexpr int ALOADS = BM / 64;
    constexpr int BLOADS = BN / 64;
    constexpr int LOADS = ALOADS + BLOADS;

    __shared__ u16 As0[BM * 32];
    __shared__ u16 Bs0[BN * 32];
    __shared__ u16 As1[BM * 32];
    __shared__ u16 Bs1[BN * 32];
    __shared__ u16 As2[BM * 32];
    __shared__ u16 Bs2[BN * 32];

    const int tid = threadIdx.x;
    const int lane = tid & 63, wv = tid >> 6;
    const int wr = wv >> 1, wc = wv & 1;

    const int gx = gridDim.x;
    const int nwg = gx * gridDim.y;
    const int bid0 = blockIdx.y * gx + blockIdx.x;
    const int nbid = (bid0 & 7) * (nwg >> 3) + (bid0 >> 3);
    const int bx = nbid % gx, by = nbid / gx;
    const int row0 = by * BM, col0 = bx * BN;

    const int Keff = (EPI == 7) ? (K >> 1) : K;
    const int k0off = (EPI == 7) ? blockIdx.z * Keff : 0;

    // EPI 9: per-segment A source (block-uniform; 1024 % BN == 0)
    const u16* Abase = (EPI == 9 && col0 >= 1024) ? A2 : A;

    const u16* pa[ALOADS];
    int ldst[ALOADS];
    #pragma unroll
    for (int i = 0; i < ALOADS; ++i) {
        const int idx = i * 256 + tid;
        const int r = idx >> 2;
        const int kob = (idx & 3) << 4;
        const int sw = kob ^ (((r >> 1) & 3) << 4);
        pa[i] = Abase + (size_t)(row0 + r) * K + k0off + (sw >> 1);
        ldst[i] = idx * 8;
    }
    const u16* pb[BLOADS];
    int ldstB[BLOADS];
    #pragma unroll
    for (int i = 0; i < BLOADS; ++i) {
        const int idx = i * 256 + tid;
        const int r = idx >> 2;
        const int kob = (idx & 3) << 4;
        const int sw = kob ^ (((r >> 1) & 3) << 4);
        pb[i] = Bt + (size_t)(col0 + r) * K + k0off + (sw >> 1);
        ldstB[i] = idx * 8;
    }

    int offa[MFR], offb[NF];
    const int rsel = lane & 15, slot = lane >> 4;
    #pragma unroll
    for (int m = 0; m < MFR; ++m) {
        const int ra = wr * (BM / 2) + m * 16 + rsel;
        offa[m] = ra * 32 + (((slot << 4) ^ (((ra >> 1) & 3) << 4)) >> 1);
    }
    #pragma unroll
    for (int n = 0; n < NF; ++n) {
        const int rb = wc * (NF * 16) + n * 16 + rsel;
        offb[n] = rb * 32 + (((slot << 4) ^ (((rb >> 1) & 3) << 4)) >> 1);
    }

    floatx4 acc[MFR][NF] = {};

#define STAGE(AA, BB, t) do {                                   \
        const int ko_ = (t) << 5;                               \
        _Pragma("unroll")                                       \
        for (int i = 0; i < ALOADS; ++i)                        \
            GLDS(pa[i] + ko_, &AA[ldst[i]]);                    \
        _Pragma("unroll")                                       \
        for (int i = 0; i < BLOADS; ++i)                        \
            GLDS(pb[i] + ko_, &BB[ldstB[i]]);                   \
    } while (0)

#define COMPUTE(AA, BB) do {                                    \
        bf16x8 af[MFR], bfr[NF];                                \
        _Pragma("unroll")                                       \
        for (int m = 0; m < MFR; ++m) af[m] = *(const bf16x8*)&AA[offa[m]]; \
        _Pragma("unroll")                                       \
        for (int n = 0; n < NF; ++n) bfr[n] = *(const bf16x8*)&BB[offb[n]]; \
        _Pragma("unroll")                                       \
        for (int m = 0; m < MFR; ++m)                           \
            _Pragma("unroll")                                   \
            for (int n = 0; n < NF; ++n)                        \
                acc[m][n] = __builtin_amdgcn_mfma_f32_16x16x32_bf16( \
                        af[m], bfr[n], acc[m][n], 0, 0, 0);     \
    } while (0)

#define PHASE(CA, CB, NA, NB, t) do {                           \
        if ((t) < nkt - 1) {                                    \
            if constexpr (LOADS == 6)                           \
                asm volatile("s_waitcnt vmcnt(6)" ::: "memory");\
            else if constexpr (LOADS == 4)                      \
                asm volatile("s_waitcnt vmcnt(4)" ::: "memory");\
            else                                                \
                asm volatile("s_waitcnt vmcnt(3)" ::: "memory");\
        } else {                                                \
            asm volatile("s_waitcnt vmcnt(0)" ::: "memory");    \
        }                                                       \
        __builtin_amdgcn_s_barrier();                           \
        __builtin_amdgcn_sched_barrier(0);                      \
        if ((t) + 2 < nkt) STAGE(NA, NB, (t) + 2);              \
        COMPUTE(CA, CB);                                        \
    } while (0)

    const int nkt = Keff >> 5;       // 32, 64, 128
    STAGE(As0, Bs0, 0);
    STAGE(As1, Bs1, 1);
    int t = 0;
    for (; t + 3 <= nkt; t += 3) {
        PHASE(As0, Bs0, As2, Bs2, t);
        PHASE(As1, Bs1, As0, Bs0, t + 1);
        PHASE(As2, Bs2, As1, Bs1, t + 2);
    }
    if (t < nkt)     PHASE(As0, Bs0, As2, Bs2, t);
    if (t + 1 < nkt) PHASE(As1, Bs1, As0, Bs0, t + 1);
#undef STAGE
#undef COMPUTE
#undef PHASE

    const int cr4 = (lane >> 4) * 4;
    const int cc = lane & 15;

    if (EPI == 7) {
        float* dst = (blockIdx.z == 0) ? (float*)Cv : (float*)o1;
        const bool addb = (blockIdx.z == 0);
        #pragma unroll
        for (int n = 0; n < NF; ++n) {
            const int col = col0 + wc * (NF * 16) + n * 16 + cc;
            const float bv = addb ? bias[col] : 0.f;
            #pragma unroll
            for (int m = 0; m < MFR; ++m) {
                const int rowb = row0 + wr * (BM / 2) + m * 16 + cr4;
                #pragma unroll
                for (int r = 0; r < 4; ++r)
                    dst[(size_t)(rowb + r) * N + col] = acc[m][n][r] + bv;
            }
        }
        return;
    }

    if (EPI == 5 || EPI == 6 || EPI == 9) {
        const int seg = col0 >> 10;
        const int vtseg = (EPI == 6) ? 1 : 2;
        u16* dst;
        if (EPI == 6) dst = (seg == 0) ? (u16*)Cv : o1;
        else          dst = (seg == 0) ? (u16*)Cv : (seg == 1 ? o1 : o2);

        if (seg == vtseg) {
            #pragma unroll
            for (int n = 0; n < NF; ++n) {
                const int col = col0 + wc * (NF * 16) + n * 16 + cc;
                const float bv = bias[col];
                const int vcol = col & 1023;
                const int h = vcol >> 6, d = vcol & 63;
                #pragma unroll
                for (int m = 0; m < MFR; ++m) {
                    const int tk = row0 + wr * (BM / 2) + m * 16 + cr4;
                    const int b = tk >> 10;
                    ushort4 o4;
                    o4.x = f2bf(acc[m][n][0] + bv);
                    o4.y = f2bf(acc[m][n][1] + bv);
                    o4.z = f2bf(acc[m][n][2] + bv);
                    o4.w = f2bf(acc[m][n][3] + bv);
                    *(ushort4*)(dst +
                        (((size_t)(b * 16 + h) * 64 + d) * 1024 + (tk & 1023))) = o4;
                }
            }
        } else {
            const float osc = ((EPI == 5 || EPI == 9) && seg == 0) ? SCLQ : 1.f;
            #pragma unroll
            for (int n = 0; n < NF; ++n) {
                const int col = col0 + wc * (NF * 16) + n * 16 + cc;
                const float bv = bias[col];
                const int oc = col & 1023;
                #pragma unroll
                for (int m = 0; m < MFR; ++m) {
                    const int rowb = row0 + wr * (BM / 2) + m * 16 + cr4;
                    #pragma unroll
                    for (int r = 0; r < 4; ++r)
                        dst[(size_t)(rowb + r) * 1024 + oc] = f2bf((acc[m][n][r] + bv) * osc);
                }
            }
        }
        return;
    }

    #pragma unroll
    for (int n = 0; n < NF; ++n) {
        const int col = col0 + wc * (NF * 16) + n * 16 + cc;
        const float bv = bias[col];
        #pragma unroll
        for (int m = 0; m < MFR; ++m) {
            const int rowb = row0 + wr * (BM / 2) + m * 16 + cr4;
            #pragma unroll
            for (int r = 0; r < 4; ++r) {
                float v = acc[m][n][r] + bv;
                const size_t o = (size_t)(rowb + r) * N + col;
                if (EPI == 2) v += u2f((unsigned)res[o] << 16);
                if (EPI == 1) v = fmaxf(v, 0.f);
                if (EPI == 8) v *= SCLQ;
                ((u16*)Cv)[o] = f2bf(v);
            }
        }
    }
}

// ---------------------------------------------------------------------------
// Fused prep: 10 weight transposes (f32->bf16, W[K,N] -> Wt[N,K]) +
// tgt/mem f32->bf16 conversion + bias concat, all in ONE dispatch.
// ---------------------------------------------------------------------------
struct PrepArgs {
    const float* w[10];
    u16* o[10];
    const float* tgt; const float* mem;
    u16* tgtb; u16* memb;
    const float* bq; const float* bk; const float* bv;      // sa biases
    const float* cbq; const float* cbk; const float* cbv;   // ca biases
    float* biasQKV; float* biasCA;
};

__global__ __launch_bounds__(256) void prep_kernel(PrepArgs p)
{
    __shared__ float ts[64][65];
    const int tid = threadIdx.x;
    int bid = blockIdx.x;

    if (bid < 4096) {
        int w, n0, k0, K, N;
        if (bid < 2048) {
            w = bid >> 8;
            const int t = bid & 255;
            n0 = (t & 15) * 64; k0 = ((t >> 4) & 15) * 64; K = 1024; N = 1024;
        } else if (bid < 3072) {
            w = 8;
            const int t = bid - 2048;
            n0 = (t & 63) * 64; k0 = (t >> 6) * 64; K = 1024; N = 4096;
        } else {
            w = 9;
            const int t = bid - 3072;
            n0 = (t & 15) * 64; k0 = (t >> 4) * 64; K = 4096; N = 1024;
        }
        const float* __restrict__ W = p.w[w];
        u16* __restrict__ Wt = p.o[w];
        const int tr = tid >> 4, tc4 = (tid & 15) * 4;
        #pragma unroll
        for (int i = 0; i < 4; ++i) {
            const float4 v = *(const float4*)(W + (size_t)(k0 + tr + i * 16) * N + n0 + tc4);
            ts[tr + i * 16][tc4 + 0] = v.x;
            ts[tr + i * 16][tc4 + 1] = v.y;
            ts[tr + i * 16][tc4 + 2] = v.z;
            ts[tr + i * 16][tc4 + 3] = v.w;
        }
        __syncthreads();
        #pragma unroll
        for (int i = 0; i < 4; ++i) {
            const int nr = tr + i * 16;
            ushort4 o;
            o.x = f2bf(ts[tc4 + 0][nr]);
            o.y = f2bf(ts[tc4 + 1][nr]);
            o.z = f2bf(ts[tc4 + 2][nr]);
            o.w = f2bf(ts[tc4 + 3][nr]);
            *(ushort4*)(Wt + (size_t)(n0 + nr) * K + k0 + tc4) = o;
        }
        return;
    }
    bid -= 4096;
    if (bid < 4096) {
        const int i = bid * 256 + tid;
        const float4 v = ((const float4*)p.tgt)[i];
        ushort4 o;
        o.x = f2bf(v.x); o.y = f2bf(v.y); o.z = f2bf(v.z); o.w = f2bf(v.w);
        ((ushort4*)p.tgtb)[i] = o;
        return;
    }
    bid -= 4096;
    if (bid < 4096) {
        const int i = bid * 256 + tid;
        const float4 v = ((const float4*)p.mem)[i];
        ushort4 o;
        o.x = f2bf(v.x); o.y = f2bf(v.y); o.z = f2bf(v.z); o.w = f2bf(v.w);
        ((ushort4*)p.memb)[i] = o;
        return;
    }
    bid -= 4096;
    const int i = bid * 256 + tid;
    if (i < 3072) {
        p.biasQKV[i] = (i < 1024) ? p.bq[i] : (i < 2048 ? p.bk[i - 1024] : p.bv[i - 2048]);
        p.biasCA[i]  = (i < 1024) ? p.cbq[i] : (i < 2048 ? p.cbk[i - 1024] : p.cbv[i - 2048]);
    }
}

// ---------------------------------------------------------------------------
// MFMA flash attention, swapped-operand, STATIC-MAX softmax.
// Q pre-scaled by 0.125*log2(e) upstream; P = exp2(s) directly.
// s_setprio(1) around MFMA clusters (T5). Causal: LJF block order —
// heavy q-tiles (qt large, qt+1 K-tiles of work) dispatch FIRST so the
// dispatch tail is filled by light blocks instead of stragglers.
// Grid (64, 16). LDS 24 KB.
// ---------------------------------------------------------------------------
template<int CAUSAL>
__global__ __launch_bounds__(256) void fattn_mfma(
        const u16* __restrict__ Q, const u16* __restrict__ K,
        const u16* __restrict__ Vt, u16* __restrict__ O)
{
    __shared__ u16 Ks[64 * 64];
    __shared__ u16 Vs[64 * 64];
    __shared__ u16 Ps[64 * 64];

    const int tid = threadIdx.x;
    const int lane = tid & 63, wv = tid >> 6;
    const int g = lane >> 4, qx = lane & 15;
    const int bh = blockIdx.x;
    const int b = bh >> 4, h = bh & 15;
    // LJF for causal: reverse qt so heaviest blocks launch first
    const int qt = CAUSAL ? (int)(gridDim.y - 1 - blockIdx.y) : (int)blockIdx.y;
    const int q0 = qt * 64;

    const size_t qkbase = (size_t)b * (1024 * 1024) + (size_t)h * 64;
    const size_t vtbase = (size_t)bh * 64 * 1024;

    const int qr = wv * 16 + qx;
    const int qg = q0 + qr;
    const int swzq = (qr & 7) << 4;

    bf16x8 qf[2];
    #pragma unroll
    for (int ks = 0; ks < 2; ++ks)
        qf[ks] = *(const bf16x8*)(Q + qkbase + (size_t)qg * 1024 + ks * 32 + g * 8);

    const int r0 = tid >> 3, s0 = tid & 7;

    float l_i = 0.f;
    floatx4 o_acc[4] = {};

    const int ktmax = CAUSAL ? qt : 15;
    for (int kt = 0; kt <= ktmax; ++kt) {
        __syncthreads();
        #pragma unroll
        for (int i = 0; i < 2; ++i) {
            const int r = i * 32 + r0;
            const uint4 kv = *(const uint4*)(K + qkbase + (size_t)(kt * 64 + r) * 1024 + s0 * 8);
            *(uint4*)((char*)Ks + r * 128 + ((s0 ^ (r & 7)) << 4)) = kv;
            const uint4 vv = *(const uint4*)(Vt + vtbase + (size_t)r * 1024 + kt * 64 + s0 * 8);
            *(uint4*)((char*)Vs + r * 128 + ((s0 ^ (r & 7)) << 4)) = vv;
        }
        __syncthreads();

        __builtin_amdgcn_s_setprio(1);
        floatx4 sa[4] = {};
        #pragma unroll
        for (int ks = 0; ks < 2; ++ks) {
            #pragma unroll
            for (int m = 0; m < 4; ++m) {
                const int rr = m * 16 + qx;
                const int sl = ks * 4 + g;
                const bf16x8 kf = *(const bf16x8*)((char*)Ks + rr * 128 + ((sl ^ (rr & 7)) << 4));
                sa[m] = __builtin_amdgcn_mfma_f32_16x16x32_bf16(kf, qf[ks], sa[m], 0, 0, 0);
            }
        }
        __builtin_amdgcn_s_setprio(0);

        float p[4][4];
        float rs = 0.f;
        #pragma unroll
        for (int m = 0; m < 4; ++m)
            #pragma unroll
            for (int r = 0; r < 4; ++r) {
                float e = exp2f(sa[m][r]);
                if (CAUSAL && kt == qt) {
                    const int kl = m * 16 + g * 4 + r;
                    if (kl > qr) e = 0.f;
                }
                p[m][r] = e;
                rs += e;
            }
        rs += __shfl_xor(rs, 16);
        rs += __shfl_xor(rs, 32);
        l_i += rs;

        #pragma unroll
        for (int m = 0; m < 4; ++m) {
            uint2 pk;
            pk.x = pk2bf(p[m][0], p[m][1]);
            pk.y = pk2bf(p[m][2], p[m][3]);
            *(uint2*)((char*)Ps + qr * 128 + ((m * 32 + g * 8) ^ swzq)) = pk;
        }

        __builtin_amdgcn_s_setprio(1);
        #pragma unroll
        for (int ks2 = 0; ks2 < 2; ++ks2) {
            const bf16x8 pf = *(const bf16x8*)((char*)Ps + qr * 128 + ((ks2 * 64 + g * 16) ^ swzq));
            #pragma unroll
            for (int n = 0; n < 4; ++n) {
                const int rv = n * 16 + qx;
                const int sl = ks2 * 4 + g;
                const bf16x8 vf = *(const bf16x8*)((char*)Vs + rv * 128 + ((sl ^ (rv & 7)) << 4));
                o_acc[n] = __builtin_amdgcn_mfma_f32_16x16x32_bf16(vf, pf, o_acc[n], 0, 0, 0);
            }
        }
        __builtin_amdgcn_s_setprio(0);
    }

    const float inv = 1.f / l_i;
    #pragma unroll
    for (int n = 0; n < 4; ++n) {
        uint2 ov;
        ov.x = pk2bf(o_acc[n][0] * inv, o_acc[n][1] * inv);
        ov.y = pk2bf(o_acc[n][2] * inv, o_acc[n][3] * inv);
        *(uint2*)((char*)Ps + qr * 128 + ((n * 32 + g * 8) ^ swzq)) = ov;
    }
    const int orow = wv * 16 + (lane >> 2);
    const int swzo = (orow & 7) << 4;
    #pragma unroll
    for (int i = 0; i < 2; ++i) {
        const int cb = ((lane & 3) * 2 + i) * 16;
        const uint4 ov = *(const uint4*)((char*)Ps + orow * 128 + (cb ^ swzo));
        *(uint4*)(O + qkbase + (size_t)(q0 + orow) * 1024 + cb / 2) = ov;
    }
}

// ---------------------------------------------------------------------------
// LayerNorm, bf16 in/out, fp32 stats. One block (256) per row of 1024.
// ---------------------------------------------------------------------------
__global__ __launch_bounds__(256) void ln_bf16_kernel(
        const u16* __restrict__ X, const float* __restrict__ g,
        const float* __restrict__ bta, u16* __restrict__ Y)
{
    __shared__ float red[4];
    const int row = blockIdx.x, tid = threadIdx.x;
    const int wave = tid >> 6, lane = tid & 63;

    const uint2 u = *(const uint2*)(X + (size_t)row * 1024 + tid * 4);
    const float x0 = bflo(u.x), x1 = bfhi(u.x), x2 = bflo(u.y), x3 = bfhi(u.y);

    float s = x0 + x1 + x2 + x3;
    #pragma unroll
    for (int off = 32; off; off >>= 1) s += __shfl_xor(s, off);
    if (lane == 0) red[wave] = s;
    __syncthreads();
    const float mu = (red[0] + red[1] + red[2] + red[3]) * (1.f / 1024.f);
    __syncthreads();

    const float d0 = x0 - mu, d1 = x1 - mu, d2 = x2 - mu, d3 = x3 - mu;
    float s2 = d0 * d0 + d1 * d1 + d2 * d2 + d3 * d3;
    #pragma unroll
    for (int off = 32; off; off >>= 1) s2 += __shfl_xor(s2, off);
    if (lane == 0) red[wave] = s2;
    __syncthreads();
    const float var = (red[0] + red[1] + red[2] + red[3]) * (1.f / 1024.f);
    const float rs = rsqrtf(var + 1e-5f);

    const float4 gg = ((const float4*)g)[tid];
    const float4 bb = ((const float4*)bta)[tid];
    ushort4 o;
    o.x = f2bf(d0 * rs * gg.x + bb.x);
    o.y = f2bf(d1 * rs * gg.y + bb.y);
    o.z = f2bf(d2 * rs * gg.z + bb.z);
    o.w = f2bf(d3 * rs * gg.w + bb.w);
    *(ushort4*)(Y + (size_t)row * 1024 + tid * 4) = o;
}

// final LayerNorm: X0 + X1 (f32 split-K partials) + bf16 residual -> f32 out
__global__ __launch_bounds__(256) void ln_res_kernel(
        const float* X0, const float* __restrict__ X1,
        const u16* __restrict__ res, const float* __restrict__ g,
        const float* __restrict__ bta, float* Y)
{
    __shared__ float red[4];
    const int row = blockIdx.x;
    const int tid = threadIdx.x;
    const int wave = tid >> 6, lane = tid & 63;

    const float4 v0 = ((const float4*)(X0 + (size_t)row * 1024))[tid];
    const float4 v1 = ((const float4*)(X1 + (size_t)row * 1024))[tid];
    const uint2 u = *(const uint2*)(res + (size_t)row * 1024 + tid * 4);
    const float x0 = v0.x + v1.x + bflo(u.x), x1 = v0.y + v1.y + bfhi(u.x);
    const float x2 = v0.z + v1.z + bflo(u.y), x3 = v0.w + v1.w + bfhi(u.y);

    float s = x0 + x1 + x2 + x3;
    #pragma unroll
    for (int off = 32; off; off >>= 1) s += __shfl_xor(s, off);
    if (lane == 0) red[wave] = s;
    __syncthreads();
    const float mu = (red[0] + red[1] + red[2] + red[3]) * (1.f / 1024.f);
    __syncthreads();

    const float d0 = x0 - mu, d1 = x1 - mu, d2 = x2 - mu, d3 = x3 - mu;
    float s2 = d0 * d0 + d1 * d1 + d2 * d2 + d3 * d3;
    #pragma unroll
    for (int off = 32; off; off >>= 1) s2 += __shfl_xor(s2, off);
    if (lane == 0) red[wave] = s2;
    __syncthreads();
    const float var = (red[0] + red[1] + red[2] + red[3]) * (1.f / 1024.f);
    const float rs = rsqrtf(var + 1e-5f);

    const float4 gg = ((const float4*)g)[tid];
    const float4 bb = ((const float4*)bta)[tid];
    float4 o;
    o.x = d0 * rs * gg.x + bb.x;
    o.y = d1 * rs * gg.y + bb.y;
    o.z = d2 * rs * gg.z + bb.z;
    o.w = d3 * rs * gg.w + bb.w;
    ((float4*)(Y + (size_t)row * 1024))[tid] = o;
}

// ---------------------------------------------------------------------------
extern "C" void kernel_launch(void* const* d_in, const int* in_sizes, int n_in,
                              void* d_out, int out_size, void* d_ws, size_t ws_size,
                              hipStream_t stream)
{
    const float* tgt    = (const float*)d_in[0];
    const float* mem    = (const float*)d_in[1];
    const float* sa_wq  = (const float*)d_in[3];
    const float* sa_bq  = (const float*)d_in[4];
    const float* sa_wk  = (const float*)d_in[5];
    const float* sa_bk  = (const float*)d_in[6];
    const float* sa_wv  = (const float*)d_in[7];
    const float* sa_bv  = (const float*)d_in[8];
    const float* sa_wo  = (const float*)d_in[9];
    const float* sa_bo  = (const float*)d_in[10];
    const float* ca_wq  = (const float*)d_in[11];
    const float* ca_bq  = (const float*)d_in[12];
    const float* ca_wk  = (const float*)d_in[13];
    const float* ca_bk  = (const float*)d_in[14];
    const float* ca_wv  = (const float*)d_in[15];
    const float* ca_bv  = (const float*)d_in[16];
    const float* ca_wo  = (const float*)d_in[17];
    const float* ca_bo  = (const float*)d_in[18];
    const float* ffn_w1 = (const float*)d_in[19];
    const float* ffn_b1 = (const float*)d_in[20];
    const float* ffn_w2 = (const float*)d_in[21];
    const float* ffn_b2 = (const float*)d_in[22];
    const float* ln1_g  = (const float*)d_in[23];
    const float* ln1_b  = (const float*)d_in[24];
    const float* ln2_g  = (const float*)d_in[25];
    const float* ln2_b  = (const float*)d_in[26];
    const float* ln3_g  = (const float*)d_in[27];
    const float* ln3_b  = (const float*)d_in[28];

    float* out = (float*)d_out;
    u16* wsb = (u16*)d_ws;
    const size_t M1 = 1024 * 1024;

    u16* Wsq = wsb + 0 * M1;
    u16* Wsk = wsb + 1 * M1;
    u16* Wsv = wsb + 2 * M1;
    u16* Wso = wsb + 3 * M1;
    u16* Wcq = wsb + 4 * M1;
    u16* Wck = wsb + 5 * M1;
    u16* Wcv = wsb + 6 * M1;
    u16* Wco = wsb + 7 * M1;
    u16* Wf1 = wsb + 8 * M1;
    u16* Wf2 = wsb + 12 * M1;

    u16* sl = wsb + 16 * M1;
    u16* s0 = sl + 0 * 4 * M1;
    u16* s1 = sl + 4 * M1;
    u16* s2 = sl + 8 * M1;
    u16* s3 = sl + 12 * M1;
    u16* s4 = sl + 16 * M1;
    u16* s5 = sl + 20 * M1;
    u16* H  = s0;

    float* part1 = (float*)wsb;

    float* biasQKV = (float*)(wsb + 40 * M1);   // [3072]
    float* biasCA  = biasQKV + 3072;            // [3072]

    const dim3 blk(256);
    const dim3 gqkv(24, 32);    // N=3072 fused QKV / fused CA (128x128)
    const dim3 g1(16, 32);      // N=1024 GEMM (128x64)
    const dim3 g4(32, 16);      // N=4096 FFN1 (256x128, MW=8)
    const dim3 gf2(8, 32, 2);   // FFN2 split-K=2 (128x128)
    const dim3 ga(64, 16);      // attention
    const dim3 gln(4096);

    PrepArgs pa;
    pa.w[0] = sa_wq; pa.o[0] = Wsq;
    pa.w[1] = sa_wk; pa.o[1] = Wsk;
    pa.w[2] = sa_wv; pa.o[2] = Wsv;
    pa.w[3] = sa_wo; pa.o[3] = Wso;
    pa.w[4] = ca_wq; pa.o[4] = Wcq;
    pa.w[5] = ca_wk; pa.o[5] = Wck;
    pa.w[6] = ca_wv; pa.o[6] = Wcv;
    pa.w[7] = ca_wo; pa.o[7] = Wco;
    pa.w[8] = ffn_w1; pa.o[8] = Wf1;
    pa.w[9] = ffn_w2; pa.o[9] = Wf2;
    pa.tgt = tgt; pa.mem = mem; pa.tgtb = s0; pa.memb = s1;
    pa.bq = sa_bq; pa.bk = sa_bk; pa.bv = sa_bv;
    pa.cbq = ca_bq; pa.cbk = ca_bk; pa.cbv = ca_bv;
    pa.biasQKV = biasQKV; pa.biasCA = biasCA;
    prep_kernel<<<12308, blk, 0, stream>>>(pa);

    // ---- self-attention ----
    // fused QKV: Q(pre-scaled)->s2, K->s3, Vt->s4
    gemm_mfma<5, 4, 4><<<gqkv, blk, 0, stream>>>(s0, Wsq, biasQKV, nullptr,
                                                 s2, s3, s4, nullptr, 3072, 1024);
    fattn_mfma<1><<<ga, blk, 0, stream>>>(s2, s3, s4, s5);
    gemm_mfma<2, 2, 4><<<g1, blk, 0, stream>>>(s5, Wso, sa_bo, s0, s2, nullptr, nullptr, nullptr, 1024, 1024);
    ln_bf16_kernel<<<gln, blk, 0, stream>>>(s2, ln1_g, ln1_b, s3);     // x1 = s3

    // ---- cross-attention ----
    // fused CA projections (EPI 9): seg0 Q from x1 (s3), seg1/2 K,Vt from mem (s1)
    gemm_mfma<9, 4, 4><<<gqkv, blk, 0, stream>>>(s3, Wcq, biasCA, nullptr,
                                                 s2, s4, s5, s1, 3072, 1024);
    fattn_mfma<0><<<ga, blk, 0, stream>>>(s2, s4, s5, s0);
    gemm_mfma<2, 2, 4><<<g1, blk, 0, stream>>>(s0, Wco, ca_bo, s3, s2, nullptr, nullptr, nullptr, 1024, 1024);
    ln_bf16_kernel<<<gln, blk, 0, stream>>>(s2, ln2_g, ln2_b, s4);     // x2 = s4

    // ---- FFN ----
    gemm_mfma<1, 4, 8><<<g4, blk, 0, stream>>>(s4, Wf1, ffn_b1, nullptr, H, nullptr, nullptr, nullptr, 4096, 1024);
    gemm_mfma<7, 4, 4><<<gf2, blk, 0, stream>>>(H, Wf2, ffn_b2, nullptr, out,
                                                (u16*)part1, nullptr, nullptr, 1024, 4096);
    ln_res_kernel<<<gln, blk, 0, stream>>>(out, part1, s4, ln3_g, ln3_b, out);
}